// Round 1
// 1278.755 us; speedup vs baseline: 1.5149x; 1.5149x over previous
//
#include <hip/hip_runtime.h>
#include <cmath>

typedef unsigned short ushort_t;
typedef unsigned char uchar_t;
typedef short short8 __attribute__((ext_vector_type(8)));
typedef float floatx4 __attribute__((ext_vector_type(4)));

#define B_GRAPH 512
#define ROWS 131072
#define IN_D 576                   // 512 LN'd feats + 64 ctx
#define FEAT_HID 1024
#define ATTN_HID 256
#define FEAT_OUT 256
#define BK 32                      // K-step; LDS row stride = 32 bf16 = 64B (linear, no pad)

// ---------- bf16 helpers (bit-level) ----------
__device__ __forceinline__ float bf2f(ushort_t h) {
    return __uint_as_float(((unsigned int)h) << 16);
}
__device__ __forceinline__ ushort_t f2bf(float f) {
    unsigned int u = __float_as_uint(f);
    u += 0x7fffu + ((u >> 16) & 1u);   // RNE
    return (ushort_t)(u >> 16);
}
__device__ __forceinline__ void load4bf(const ushort_t* p, float f[4]) {
    uint2 u = *(const uint2*)p;
    f[0] = __uint_as_float(u.x << 16);
    f[1] = __uint_as_float(u.x & 0xffff0000u);
    f[2] = __uint_as_float(u.y << 16);
    f[3] = __uint_as_float(u.y & 0xffff0000u);
}

// ---------- runtime dtype detection ----------
// flags[0]: 1 if float inputs are fp32, 0 if bf16
// flags[1]: 1 if mask is packed bytes, 0 if int32
__global__ void detect_kernel(const void* nodes, const void* maskp, int* flags) {
    const int t = threadIdx.x;
    const ushort_t* nb = (const ushort_t*)nodes;
    int cnt = 0;
    for (int i = t; i < 4096; i += 256) {
        unsigned e = ((unsigned)nb[i] >> 7) & 0xffu;   // bf16 exponent field
        if (e >= 147u) cnt++;                          // |x| >= 2^20: impossible for N(0,1) bf16
    }
    const unsigned* mw = (const unsigned*)maskp;
    int mcnt = 0;
    for (int i = t; i < 16384; i += 256) {             // 64 KiB: within either encoding
        if (mw[i] > 1u) mcnt++;
    }
    __shared__ int r1[256], r2[256];
    r1[t] = cnt; r2[t] = mcnt; __syncthreads();
    for (int off = 128; off > 0; off >>= 1) {
        if (t < off) { r1[t] += r1[t + off]; r2[t] += r2[t + off]; }
        __syncthreads();
    }
    if (t == 0) { flags[0] = (r1[0] > 64) ? 1 : 0; flags[1] = (r2[0] > 16) ? 1 : 0; }
}

__device__ __forceinline__ float loadany(const void* p, size_t i, int flag) {
    return flag ? ((const float*)p)[i] : bf2f(((const ushort_t*)p)[i]);
}
__device__ __forceinline__ bool maskany(const void* p, size_t i, int flagM) {
    return flagM ? (((const uchar_t*)p)[i] != 0) : (((const int*)p)[i] != 0);
}

// ---------- merged small-tensor convert -> canonical bf16 ----------
// jobs (element counts): globs 32768 | ln_g 512 | ln_b 512 | fb1 1024 |
//                        fb2 256 | ab1 256 | ab2 4      total 35332
__global__ __launch_bounds__(256)
void convert_all(const void* globs, const void* lng, const void* lnb,
                 const void* fb1, const void* fb2, const void* ab1, const void* ab2,
                 ushort_t* gcan, ushort_t* lgc, ushort_t* lbc,
                 ushort_t* fb1c, ushort_t* fb2c, ushort_t* ab1c, ushort_t* ab2c,
                 const int* flags) {
    const int flag = flags[0];
    int i = blockIdx.x * 256 + threadIdx.x;
    if (i < 32768) { gcan[i] = f2bf(loadany(globs, i, flag)); return; }
    i -= 32768;
    if (i < 512)   { lgc[i]  = f2bf(loadany(lng,   i, flag)); return; }
    i -= 512;
    if (i < 512)   { lbc[i]  = f2bf(loadany(lnb,   i, flag)); return; }
    i -= 512;
    if (i < 1024)  { fb1c[i] = f2bf(loadany(fb1,   i, flag)); return; }
    i -= 1024;
    if (i < 256)   { fb2c[i] = f2bf(loadany(fb2,   i, flag)); return; }
    i -= 256;
    if (i < 256)   { ab1c[i] = f2bf(loadany(ab1,   i, flag)); return; }
    i -= 256;
    if (i < 4)     { ab2c[i] = f2bf(loadany(ab2,   i, flag)); }
}

// ---------- merged weight transposes [R,C] -> canonical bf16 [C,R] ----------
// jobs: fw1 576x1024 | fw2 1024x256 | aw1 576x256 | aw2 256x4   total 1,000,448
__global__ __launch_bounds__(256)
void transpose_all(const void* fw1, const void* fw2, const void* aw1, const void* aw2,
                   ushort_t* fw1t, ushort_t* fw2t, ushort_t* aw1t, ushort_t* aw2t,
                   const int* flags) {
    const int flag = flags[0];
    int i = blockIdx.x * 256 + threadIdx.x;
    if (i < 576 * 1024) {
        int r = i >> 10, c = i & 1023;
        fw1t[(size_t)c * 576 + r] = f2bf(loadany(fw1, i, flag)); return;
    }
    i -= 576 * 1024;
    if (i < 1024 * 256) {
        int r = i >> 8, c = i & 255;
        fw2t[(size_t)c * 1024 + r] = f2bf(loadany(fw2, i, flag)); return;
    }
    i -= 1024 * 256;
    if (i < 576 * 256) {
        int r = i >> 8, c = i & 255;
        aw1t[(size_t)c * 576 + r] = f2bf(loadany(aw1, i, flag)); return;
    }
    i -= 576 * 256;
    if (i < 256 * 4) {
        int r = i >> 2, c = i & 3;
        aw2t[(size_t)c * 256 + r] = f2bf(loadany(aw2, i, flag));
    }
}

// ---------- LN over 512 + concat canonical ctx -> inp[CH][576] bf16 ----------
__global__ __launch_bounds__(256)
void ln_concat_kernel(const void* __restrict__ nodes, const void* __restrict__ pe,
                      const ushort_t* __restrict__ gcan,   // canonical globs [512*64]
                      const ushort_t* __restrict__ lg, const ushort_t* __restrict__ lb,
                      ushort_t* __restrict__ inp, int row0, const int* __restrict__ flags) {
    const int flag = flags[0];
    const int row  = blockIdx.x * 4 + (threadIdx.x >> 6);   // chunk-local
    const int lane = threadIdx.x & 63;
    const size_t grow = (size_t)row0 + row;
    float xa[4], xb[4];
    if (flag) {
        float4 a = *(const float4*)((const float*)nodes + grow * 256 + lane * 4);
        float4 b = *(const float4*)((const float*)pe    + grow * 256 + lane * 4);
        xa[0]=a.x; xa[1]=a.y; xa[2]=a.z; xa[3]=a.w;
        xb[0]=b.x; xb[1]=b.y; xb[2]=b.z; xb[3]=b.w;
    } else {
        load4bf((const ushort_t*)nodes + grow * 256 + lane * 4, xa);
        load4bf((const ushort_t*)pe    + grow * 256 + lane * 4, xb);
    }
    float s = 0.f, q = 0.f;
#pragma unroll
    for (int j = 0; j < 4; j++) { s += xa[j] + xb[j]; q += xa[j]*xa[j] + xb[j]*xb[j]; }
#pragma unroll
    for (int m = 1; m < 64; m <<= 1) { s += __shfl_xor(s, m, 64); q += __shfl_xor(q, m, 64); }
    const float mu   = s * (1.0f / 512.0f);
    const float var  = q * (1.0f / 512.0f) - mu * mu;
    const float rstd = rsqrtf(fmaxf(var, 0.f) + 1e-5f);
    float ga[4], gb[4], ba[4], bb[4];
    load4bf(lg + lane * 4, ga);  load4bf(lg + 256 + lane * 4, gb);
    load4bf(lb + lane * 4, ba);  load4bf(lb + 256 + lane * 4, bb);
    ushort_t r0[4], r1[4];
#pragma unroll
    for (int j = 0; j < 4; j++) {
        r0[j] = f2bf((xa[j] - mu) * rstd * ga[j] + ba[j]);
        r1[j] = f2bf((xb[j] - mu) * rstd * gb[j] + bb[j]);
    }
    ushort_t* op = inp + (size_t)row * IN_D;
    uint2 p0, p1;
    p0.x = (unsigned)r0[0] | ((unsigned)r0[1] << 16);
    p0.y = (unsigned)r0[2] | ((unsigned)r0[3] << 16);
    p1.x = (unsigned)r1[0] | ((unsigned)r1[1] << 16);
    p1.y = (unsigned)r1[2] | ((unsigned)r1[3] << 16);
    *(uint2*)(op + lane * 4)       = p0;
    *(uint2*)(op + 256 + lane * 4) = p1;
    op[512 + lane] = gcan[(grow >> 8) * 64 + lane];
}

// ---------- canonical-bf16 MFMA GEMM core (m97 structure) ----------
// A[M,K] rm, Bt[N,K] rm. 128x128 tile, 4 waves 2x2, wave 64x64 = 4x4 MFMA
// 16x16x32 bf16. BK=32. Staging: global_load_lds width 16 into LINEAR LDS
// [128][32] (row = 64B). Frag ds_read_b128 covers a contiguous 1KiB region
// per wave -> conflict-free. (guide §5 ladder step 3: 517 -> 874 TF)
struct GemmCore {
    floatx4 acc[4][4];
    int wm, wn, r16, quad;
};

__device__ __forceinline__ void gload16(const ushort_t* g, ushort_t* l) {
    __builtin_amdgcn_global_load_lds(
        (const __attribute__((address_space(1))) unsigned int*)g,
        (__attribute__((address_space(3))) unsigned int*)l, 16, 0, 0);
}

__device__ __forceinline__ void gemm_core(GemmCore& g,
        const ushort_t* __restrict__ A, const ushort_t* __restrict__ Bt,
        int m0, int n0, int K, ushort_t* As, ushort_t* Bs) {
    const int tid = threadIdx.x;
    const int wave = tid >> 6, lane = tid & 63;
    g.wm = (wave >> 1) * 64; g.wn = (wave & 1) * 64;
    g.r16 = lane & 15; g.quad = lane >> 4;
#pragma unroll
    for (int i = 0; i < 4; i++)
#pragma unroll
        for (int j = 0; j < 4; j++) g.acc[i][j] = (floatx4){0.f, 0.f, 0.f, 0.f};

    // wave w stages tile rows [w*32, w*32+32): 2 insts x 16 rows.
    // lane l of an inst covers LDS elem offset l*8 -> row l>>2, col (l&3)*8.
    const int srow = wave * 32 + (lane >> 2);
    const int scol = (lane & 3) * 8;
    const ushort_t* Ag0 = A  + (size_t)(m0 + srow) * K + scol;
    const ushort_t* Ag1 = Ag0 + (size_t)16 * K;
    const ushort_t* Bg0 = Bt + (size_t)(n0 + srow) * K + scol;
    const ushort_t* Bg1 = Bg0 + (size_t)16 * K;
    ushort_t* As0 = As + wave * 32 * BK;      // wave-uniform LDS bases
    ushort_t* As1 = As0 + 16 * BK;
    ushort_t* Bs0 = Bs + wave * 32 * BK;
    ushort_t* Bs1 = Bs0 + 16 * BK;

    for (int k0 = 0; k0 < K; k0 += BK) {
        __syncthreads();                       // WAR: prev iter's ds_reads done
        gload16(Ag0 + k0, As0);
        gload16(Ag1 + k0, As1);
        gload16(Bg0 + k0, Bs0);
        gload16(Bg1 + k0, Bs1);
        __syncthreads();                       // RAW: vmcnt(0) drained here
        short8 af[4], bg[4];
#pragma unroll
        for (int i = 0; i < 4; i++)
            af[i] = *(const short8*)&As[(g.wm + i * 16 + g.r16) * BK + g.quad * 8];
#pragma unroll
        for (int i = 0; i < 4; i++)
            bg[i] = *(const short8*)&Bs[(g.wn + i * 16 + g.r16) * BK + g.quad * 8];
#pragma unroll
        for (int mi = 0; mi < 4; mi++)
#pragma unroll
            for (int ni = 0; ni < 4; ni++)
                g.acc[mi][ni] = __builtin_amdgcn_mfma_f32_16x16x32_bf16(
                    af[mi], bg[ni], g.acc[mi][ni], 0, 0, 0);
    }
}

// out = silu(acc + bias), canonical bf16 out [M,N] (chunk-local)
__global__ __launch_bounds__(256)
void gemm_silu(const ushort_t* __restrict__ A, const ushort_t* __restrict__ Bt,
               const ushort_t* __restrict__ bias, ushort_t* __restrict__ out,
               int N, int K) {
    __shared__ __align__(16) ushort_t As[128 * BK];
    __shared__ __align__(16) ushort_t Bs[128 * BK];
    const int m0 = blockIdx.x * 128, n0 = blockIdx.y * 128;
    GemmCore g;
    gemm_core(g, A, Bt, m0, n0, K, As, Bs);
#pragma unroll
    for (int mi = 0; mi < 4; mi++) {
        const int rbase = m0 + g.wm + mi * 16 + g.quad * 4;
#pragma unroll
        for (int ni = 0; ni < 4; ni++) {
            const int col = n0 + g.wn + ni * 16 + g.r16;
            const float bv = bf2f(bias[col]);
#pragma unroll
            for (int r = 0; r < 4; r++) {
                float v = g.acc[mi][ni][r] + bv;
                v = v / (1.0f + expf(-v));
                out[(size_t)(rbase + r) * N + col] = f2bf(v);
            }
        }
    }
}

// out = mask ? acc+bias+resid : resid  (writes d_out in detected dtype)
__global__ __launch_bounds__(256)
void gemm_out(const ushort_t* __restrict__ A, const ushort_t* __restrict__ Bt,
              const ushort_t* __restrict__ bias, void* __restrict__ out,
              const void* __restrict__ mask, const void* __restrict__ resid,
              int row0, int K, const int* __restrict__ flags) {
    __shared__ __align__(16) ushort_t As[128 * BK];
    __shared__ __align__(16) ushort_t Bs[128 * BK];
    const int flag = flags[0], flagM = flags[1];
    const int m0 = blockIdx.x * 128, n0 = blockIdx.y * 128;
    GemmCore g;
    gemm_core(g, A, Bt, m0, n0, K, As, Bs);
#pragma unroll
    for (int mi = 0; mi < 4; mi++) {
        const int rbase = m0 + g.wm + mi * 16 + g.quad * 4;
#pragma unroll
        for (int ni = 0; ni < 4; ni++) {
            const int col = n0 + g.wn + ni * 16 + g.r16;
            const float bv = bf2f(bias[col]);
#pragma unroll
            for (int r = 0; r < 4; r++) {
                const size_t grow = (size_t)row0 + rbase + r;
                const float nd = loadany(resid, grow * FEAT_OUT + col, flag);
                const bool mk = maskany(mask, grow, flagM);
                float v = mk ? (g.acc[mi][ni][r] + bv + nd) : nd;
                if (flag) ((float*)out)[grow * FEAT_OUT + col] = v;
                else      ((ushort_t*)out)[grow * FEAT_OUT + col] = f2bf(v);
            }
        }
    }
}

// ---------- scores = ha[.,256] @ aw2t[4,256]^T + ab2 ----------
__global__ __launch_bounds__(256)
void scores_kernel(const ushort_t* __restrict__ ha,   // chunk-local [CH,256]
                   const ushort_t* __restrict__ aw2t,
                   const ushort_t* __restrict__ ab2c,
                   float* __restrict__ scores, int row0) {
    const int row  = blockIdx.x * 4 + (threadIdx.x >> 6);
    const int lane = threadIdx.x & 63;
    float x[4];
    load4bf(ha + (size_t)row * 256 + lane * 4, x);
    float acc[4];
#pragma unroll
    for (int h = 0; h < 4; h++) {
        float wv[4];
        load4bf(aw2t + h * 256 + lane * 4, wv);
        acc[h] = x[0]*wv[0] + x[1]*wv[1] + x[2]*wv[2] + x[3]*wv[3];
    }
#pragma unroll
    for (int m = 1; m < 64; m <<= 1)
#pragma unroll
        for (int h = 0; h < 4; h++) acc[h] += __shfl_xor(acc[h], m, 64);
    if (lane == 0) {
#pragma unroll
        for (int h = 0; h < 4; h++)
            scores[((size_t)row0 + row) * 4 + h] = acc[h] + bf2f(ab2c[h]);
    }
}

// ---------- masked softmax over the 256 nodes of each graph ----------
__global__ __launch_bounds__(256)
void softmax_kernel(const float* __restrict__ scores, const void* __restrict__ mask,
                    float* __restrict__ w, const int* __restrict__ flags) {
    const int flagM = flags[1];
    const int b = blockIdx.x, n = threadIdx.x;
    const int idx = b * 256 + n;
    float4 s = *(const float4*)(scores + (size_t)idx * 4);
    s.x *= 0.0625f; s.y *= 0.0625f; s.z *= 0.0625f; s.w *= 0.0625f;  // /sqrt(256)
    const bool mk = maskany(mask, idx, flagM);
    __shared__ float4 red[256];
    float4 v;
    v.x = mk ? s.x : -3.0e38f; v.y = mk ? s.y : -3.0e38f;
    v.z = mk ? s.z : -3.0e38f; v.w = mk ? s.w : -3.0e38f;
    red[n] = v; __syncthreads();
    for (int off = 128; off > 0; off >>= 1) {
        if (n < off) {
            float4 o = red[n + off], c = red[n];
            c.x = fmaxf(c.x, o.x); c.y = fmaxf(c.y, o.y);
            c.z = fmaxf(c.z, o.z); c.w = fmaxf(c.w, o.w);
            red[n] = c;
        }
        __syncthreads();
    }
    float4 mx = red[0]; __syncthreads();
    float4 e;
    e.x = mk ? expf(s.x - mx.x) : 0.f; e.y = mk ? expf(s.y - mx.y) : 0.f;
    e.z = mk ? expf(s.z - mx.z) : 0.f; e.w = mk ? expf(s.w - mx.w) : 0.f;
    red[n] = e; __syncthreads();
    for (int off = 128; off > 0; off >>= 1) {
        if (n < off) {
            float4 o = red[n + off], c = red[n];
            c.x += o.x; c.y += o.y; c.z += o.z; c.w += o.w;
            red[n] = c;
        }
        __syncthreads();
    }
    float4 sm = red[0];
    const float ix = (sm.x > 0.f) ? 1.f / sm.x : 0.f;
    const float iy = (sm.y > 0.f) ? 1.f / sm.y : 0.f;
    const float iz = (sm.z > 0.f) ? 1.f / sm.z : 0.f;
    const float iw = (sm.w > 0.f) ? 1.f / sm.w : 0.f;
    float4 r; r.x = e.x * ix; r.y = e.y * iy; r.z = e.z * iz; r.w = e.w * iw;
    *(float4*)(w + (size_t)idx * 4) = r;
}

// ---------- pooled[b][d] = sum_n new_nodes[b,n,d] * w[b,n,d>>6] ----------
__global__ __launch_bounds__(256)
void pooled_kernel(const void* __restrict__ dout, const float* __restrict__ w,
                   const int* __restrict__ flags) {
    const int flag = flags[0];
    const int b = blockIdx.x, t = threadIdx.x;
    __shared__ float wsh[1024];
    const float* wb = w + (size_t)b * 1024;
    for (int i = t; i < 1024; i += 256) wsh[i] = wb[i];
    __syncthreads();
    const int h = t >> 6;
    float acc = 0.f;
    const size_t base = (size_t)b * 65536;
    if (flag) {
        const float* nn = (const float*)dout + base;
#pragma unroll 4
        for (int n = 0; n < 256; n++) acc += nn[(size_t)n * 256 + t] * wsh[n * 4 + h];
        ((float*)dout)[(size_t)ROWS * 256 + (size_t)b * 256 + t] = acc;
    } else {
        const ushort_t* nn = (const ushort_t*)dout + base;
#pragma unroll 4
        for (int n = 0; n < 256; n++) acc += bf2f(nn[(size_t)n * 256 + t]) * wsh[n * 4 + h];
        ((ushort_t*)dout)[(size_t)ROWS * 256 + (size_t)b * 256 + t] = f2bf(acc);
    }
}

extern "C" void kernel_launch(void* const* d_in, const int* in_sizes, int n_in,
                              void* d_out, int out_size, void* d_ws, size_t ws_size,
                              hipStream_t stream) {
    (void)in_sizes; (void)n_in; (void)out_size;
    const void* nodes = d_in[0];
    const void* pe    = d_in[1];
    const void* mask  = d_in[2];
    const void* globs = d_in[3];
    const void* ln_g  = d_in[4];
    const void* ln_b  = d_in[5];
    const void* fw1   = d_in[6];
    const void* fb1   = d_in[7];
    const void* fw2   = d_in[8];
    const void* fb2   = d_in[9];
    const void* aw1   = d_in[10];
    const void* ab1   = d_in[11];
    const void* aw2   = d_in[12];
    const void* ab2   = d_in[13];

    // chunk size: 16384 rows (64 whole graphs) if the workspace allows (~68 MB),
    // else fall back to the proven 8192-row layout (~37 MB).
    const int CHR = (ws_size >= (size_t)72 * 1024 * 1024) ? 16384 : 8192;

    char* ws = (char*)d_ws;
    size_t o = 0;
    auto take = [&](size_t bytes) -> char* {
        char* p = ws + o;
        o += (bytes + 255) & ~(size_t)255;
        return p;
    };
    ushort_t* inp  = (ushort_t*)take((size_t)CHR * IN_D * 2);
    ushort_t* h    = (ushort_t*)take((size_t)CHR * FEAT_HID * 2);
    ushort_t* ha   = (ushort_t*)take((size_t)CHR * ATTN_HID * 2);
    float*    sc   = (float*)   take((size_t)ROWS * 4 * 4);
    float*    wsm  = (float*)   take((size_t)ROWS * 4 * 4);
    ushort_t* fw1t = (ushort_t*)take(576 * 1024 * 2);
    ushort_t* fw2t = (ushort_t*)take(1024 * 256 * 2);
    ushort_t* aw1t = (ushort_t*)take(576 * 256 * 2);
    ushort_t* aw2t = (ushort_t*)take(256 * 4 * 2);
    ushort_t* gcan = (ushort_t*)take(32768 * 2);
    ushort_t* lgc  = (ushort_t*)take(512 * 2);
    ushort_t* lbc  = (ushort_t*)take(512 * 2);
    ushort_t* fb1c = (ushort_t*)take(1024 * 2);
    ushort_t* fb2c = (ushort_t*)take(256 * 2);
    ushort_t* ab1c = (ushort_t*)take(256 * 2);
    ushort_t* ab2c = (ushort_t*)take(4 * 2);
    int*      flags= (int*)     take(64);

    detect_kernel<<<1, 256, 0, stream>>>(nodes, mask, flags);
    convert_all<<<139, 256, 0, stream>>>(globs, ln_g, ln_b, fb1, fb2, ab1, ab2,
                                         gcan, lgc, lbc, fb1c, fb2c, ab1c, ab2c, flags);
    transpose_all<<<3908, 256, 0, stream>>>(fw1, fw2, aw1, aw2,
                                            fw1t, fw2t, aw1t, aw2t, flags);

    const int nchunk = ROWS / CHR;
    for (int c = 0; c < nchunk; c++) {
        const int row0 = c * CHR;
        ln_concat_kernel<<<CHR / 4, 256, 0, stream>>>(nodes, pe, gcan, lgc, lbc,
                                                      inp, row0, flags);
        gemm_silu<<<dim3(CHR / 128, FEAT_HID / 128), 256, 0, stream>>>(
            inp, fw1t, fb1c, h, FEAT_HID, IN_D);
        gemm_silu<<<dim3(CHR / 128, ATTN_HID / 128), 256, 0, stream>>>(
            inp, aw1t, ab1c, ha, ATTN_HID, IN_D);
        scores_kernel<<<CHR / 4, 256, 0, stream>>>(ha, aw2t, ab2c, sc, row0);
        gemm_out<<<dim3(CHR / 128, FEAT_OUT / 128), 256, 0, stream>>>(
            h, fw2t, fb2c, d_out, mask, nodes, row0, FEAT_HID, flags);
    }

    softmax_kernel<<<B_GRAPH, 256, 0, stream>>>(sc, mask, wsm, flags);
    pooled_kernel<<<B_GRAPH, 256, 0, stream>>>(d_out, wsm, flags);
}

// Round 2
// 1055.946 us; speedup vs baseline: 1.8346x; 1.2110x over previous
//
#include <hip/hip_runtime.h>
#include <cmath>

typedef unsigned short ushort_t;
typedef unsigned char uchar_t;
typedef short short8 __attribute__((ext_vector_type(8)));
typedef float floatx4 __attribute__((ext_vector_type(4)));

#define B_GRAPH 512
#define ROWS 131072
#define IN_D 576                   // 512 LN'd feats + 64 ctx
#define FEAT_HID 1024
#define ATTN_HID 256
#define NCAT 1280                  // fused feat1(1024) + attn1(256) output cols
#define FEAT_OUT 256
#define BK 32                      // K-step; LDS row = 32 bf16 = 64B (linear)
#define NBUF 3                     // depth-2 prefetch pipeline
#define TILE_ELEMS (128 * BK)      // 4096 ushorts per tile buffer
#define BUF_BYTES  (TILE_ELEMS * 2)

// ---------- bf16 helpers (bit-level) ----------
__device__ __forceinline__ float bf2f(ushort_t h) {
    return __uint_as_float(((unsigned int)h) << 16);
}
__device__ __forceinline__ ushort_t f2bf(float f) {
    unsigned int u = __float_as_uint(f);
    u += 0x7fffu + ((u >> 16) & 1u);   // RNE
    return (ushort_t)(u >> 16);
}
__device__ __forceinline__ void load4bf(const ushort_t* p, float f[4]) {
    uint2 u = *(const uint2*)p;
    f[0] = __uint_as_float(u.x << 16);
    f[1] = __uint_as_float(u.x & 0xffff0000u);
    f[2] = __uint_as_float(u.y << 16);
    f[3] = __uint_as_float(u.y & 0xffff0000u);
}

// ---------- runtime dtype detection ----------
__global__ void detect_kernel(const void* nodes, const void* maskp, int* flags) {
    const int t = threadIdx.x;
    const ushort_t* nb = (const ushort_t*)nodes;
    int cnt = 0;
    for (int i = t; i < 4096; i += 256) {
        unsigned e = ((unsigned)nb[i] >> 7) & 0xffu;
        if (e >= 147u) cnt++;
    }
    const unsigned* mw = (const unsigned*)maskp;
    int mcnt = 0;
    for (int i = t; i < 16384; i += 256) {
        if (mw[i] > 1u) mcnt++;
    }
    __shared__ int r1[256], r2[256];
    r1[t] = cnt; r2[t] = mcnt; __syncthreads();
    for (int off = 128; off > 0; off >>= 1) {
        if (t < off) { r1[t] += r1[t + off]; r2[t] += r2[t + off]; }
        __syncthreads();
    }
    if (t == 0) { flags[0] = (r1[0] > 64) ? 1 : 0; flags[1] = (r2[0] > 16) ? 1 : 0; }
}

__device__ __forceinline__ float loadany(const void* p, size_t i, int flag) {
    return flag ? ((const float*)p)[i] : bf2f(((const ushort_t*)p)[i]);
}
__device__ __forceinline__ bool maskany(const void* p, size_t i, int flagM) {
    return flagM ? (((const uchar_t*)p)[i] != 0) : (((const int*)p)[i] != 0);
}

// ---------- merged small-tensor convert -> canonical bf16 ----------
// globs 32768 | ln_g 512 | ln_b 512 | bcat: fb1 1024 + ab1 256 | fb2 256 | ab2 4
__global__ __launch_bounds__(256)
void convert_all(const void* globs, const void* lng, const void* lnb,
                 const void* fb1, const void* fb2, const void* ab1, const void* ab2,
                 ushort_t* gcan, ushort_t* lgc, ushort_t* lbc,
                 ushort_t* bcat, ushort_t* fb2c, ushort_t* ab2c,
                 const int* flags) {
    const int flag = flags[0];
    int i = blockIdx.x * 256 + threadIdx.x;
    if (i < 32768) { gcan[i] = f2bf(loadany(globs, i, flag)); return; }
    i -= 32768;
    if (i < 512)   { lgc[i]  = f2bf(loadany(lng,   i, flag)); return; }
    i -= 512;
    if (i < 512)   { lbc[i]  = f2bf(loadany(lnb,   i, flag)); return; }
    i -= 512;
    if (i < 1024)  { bcat[i] = f2bf(loadany(fb1,   i, flag)); return; }
    i -= 1024;
    if (i < 256)   { bcat[1024 + i] = f2bf(loadany(ab1, i, flag)); return; }
    i -= 256;
    if (i < 256)   { fb2c[i] = f2bf(loadany(fb2,   i, flag)); return; }
    i -= 256;
    if (i < 4)     { ab2c[i] = f2bf(loadany(ab2,   i, flag)); }
}

// ---------- merged weight transposes -> canonical bf16 [C,R] ----------
// w1cat rows 0..1023 = fw1 cols, rows 1024..1279 = aw1 cols (stride 576)
__global__ __launch_bounds__(256)
void transpose_all(const void* fw1, const void* fw2, const void* aw1, const void* aw2,
                   ushort_t* w1cat, ushort_t* fw2t, ushort_t* aw2t,
                   const int* flags) {
    const int flag = flags[0];
    int i = blockIdx.x * 256 + threadIdx.x;
    if (i < 576 * 1024) {
        int r = i >> 10, c = i & 1023;
        w1cat[(size_t)c * 576 + r] = f2bf(loadany(fw1, i, flag)); return;
    }
    i -= 576 * 1024;
    if (i < 1024 * 256) {
        int r = i >> 8, c = i & 255;
        fw2t[(size_t)c * 1024 + r] = f2bf(loadany(fw2, i, flag)); return;
    }
    i -= 1024 * 256;
    if (i < 576 * 256) {
        int r = i >> 8, c = i & 255;
        w1cat[(size_t)(1024 + c) * 576 + r] = f2bf(loadany(aw1, i, flag)); return;
    }
    i -= 576 * 256;
    if (i < 256 * 4) {
        int r = i >> 2, c = i & 3;
        aw2t[(size_t)c * 256 + r] = f2bf(loadany(aw2, i, flag));
    }
}

// ---------- LN over 512 + concat canonical ctx -> inp[CH][576] bf16 ----------
__global__ __launch_bounds__(256)
void ln_concat_kernel(const void* __restrict__ nodes, const void* __restrict__ pe,
                      const ushort_t* __restrict__ gcan,
                      const ushort_t* __restrict__ lg, const ushort_t* __restrict__ lb,
                      ushort_t* __restrict__ inp, int row0, const int* __restrict__ flags) {
    const int flag = flags[0];
    const int row  = blockIdx.x * 4 + (threadIdx.x >> 6);
    const int lane = threadIdx.x & 63;
    const size_t grow = (size_t)row0 + row;
    float xa[4], xb[4];
    if (flag) {
        float4 a = *(const float4*)((const float*)nodes + grow * 256 + lane * 4);
        float4 b = *(const float4*)((const float*)pe    + grow * 256 + lane * 4);
        xa[0]=a.x; xa[1]=a.y; xa[2]=a.z; xa[3]=a.w;
        xb[0]=b.x; xb[1]=b.y; xb[2]=b.z; xb[3]=b.w;
    } else {
        load4bf((const ushort_t*)nodes + grow * 256 + lane * 4, xa);
        load4bf((const ushort_t*)pe    + grow * 256 + lane * 4, xb);
    }
    float s = 0.f, q = 0.f;
#pragma unroll
    for (int j = 0; j < 4; j++) { s += xa[j] + xb[j]; q += xa[j]*xa[j] + xb[j]*xb[j]; }
#pragma unroll
    for (int m = 1; m < 64; m <<= 1) { s += __shfl_xor(s, m, 64); q += __shfl_xor(q, m, 64); }
    const float mu   = s * (1.0f / 512.0f);
    const float var  = q * (1.0f / 512.0f) - mu * mu;
    const float rstd = rsqrtf(fmaxf(var, 0.f) + 1e-5f);
    float ga[4], gb[4], ba[4], bb[4];
    load4bf(lg + lane * 4, ga);  load4bf(lg + 256 + lane * 4, gb);
    load4bf(lb + lane * 4, ba);  load4bf(lb + 256 + lane * 4, bb);
    ushort_t r0[4], r1[4];
#pragma unroll
    for (int j = 0; j < 4; j++) {
        r0[j] = f2bf((xa[j] - mu) * rstd * ga[j] + ba[j]);
        r1[j] = f2bf((xb[j] - mu) * rstd * gb[j] + bb[j]);
    }
    ushort_t* op = inp + (size_t)row * IN_D;
    uint2 p0, p1;
    p0.x = (unsigned)r0[0] | ((unsigned)r0[1] << 16);
    p0.y = (unsigned)r0[2] | ((unsigned)r0[3] << 16);
    p1.x = (unsigned)r1[0] | ((unsigned)r1[1] << 16);
    p1.y = (unsigned)r1[2] | ((unsigned)r1[3] << 16);
    *(uint2*)(op + lane * 4)       = p0;
    *(uint2*)(op + 256 + lane * 4) = p1;
    op[512 + lane] = gcan[(grow >> 8) * 64 + lane];
}

// ---------- pipelined MFMA GEMM core (T3/T4: depth-2 prefetch, counted vmcnt)
// A[M,*] row-stride lda, Bt[N,K] rm. 128x128 tile, 4 waves 2x2, 4x4 MFMA
// 16x16x32 bf16. 3 LDS buffers (48 KB). Per K-step: counted s_waitcnt vmcnt(4)
// (never 0 in steady state) + raw s_barrier; issue tile t+2 AFTER barrier
// (buffer (t+2)%3 != reader's t%3 -> race-free); fragments via inline-asm
// ds_read_b128 + lgkmcnt(0) + sched_barrier(0) (guide rule 18) so the
// waitcnt pass cannot re-insert a vmcnt(0) drain.
struct GemmCore {
    floatx4 acc[4][4];
    int wm, wn, r16, quad;
};

__device__ __forceinline__ void gload16(const ushort_t* g, ushort_t* l) {
    __builtin_amdgcn_global_load_lds(
        (const __attribute__((address_space(1))) unsigned int*)g,
        (__attribute__((address_space(3))) unsigned int*)l, 16, 0, 0);
}
__device__ __forceinline__ unsigned lds_off(const void* p) {
    return (unsigned)(size_t)(const __attribute__((address_space(3))) char*)p;
}

__device__ __forceinline__ void gemm_core(GemmCore& g,
        const ushort_t* __restrict__ A, int lda, const ushort_t* __restrict__ Bt,
        int m0, int n0, int K, ushort_t* As, ushort_t* Bs) {
    const int tid = threadIdx.x;
    const int wave = tid >> 6, lane = tid & 63;
    g.wm = (wave >> 1) * 64; g.wn = (wave & 1) * 64;
    g.r16 = lane & 15; g.quad = lane >> 4;
#pragma unroll
    for (int i = 0; i < 4; i++)
#pragma unroll
        for (int j = 0; j < 4; j++) g.acc[i][j] = (floatx4){0.f, 0.f, 0.f, 0.f};

    // wave w stages tile rows [w*32, w*32+32): 2 gload16 x 16 rows each (A and B).
    const int srow = wave * 32 + (lane >> 2);
    const int scol = (lane & 3) * 8;
    const ushort_t* Ag = A + (size_t)(m0 + srow) * lda + scol;
    const ushort_t* Bg = Bt + (size_t)(n0 + srow) * K + scol;
    const int woff = wave * 32 * BK;

    const unsigned a_lane = lds_off(As) + (unsigned)(((g.wm + g.r16) * BK + g.quad * 8) * 2);
    const unsigned b_lane = lds_off(Bs) + (unsigned)(((g.wn + g.r16) * BK + g.quad * 8) * 2);

    const int NT = K / BK;
    // prologue: prefetch tiles 0,1 into buffers 0,1
    gload16(Ag, As + woff);
    gload16(Ag + 16 * (size_t)lda, As + woff + 16 * BK);
    gload16(Bg, Bs + woff);
    gload16(Bg + 16 * (size_t)K,  Bs + woff + 16 * BK);
    if (NT > 1) {
        gload16(Ag + BK, As + TILE_ELEMS + woff);
        gload16(Ag + BK + 16 * (size_t)lda, As + TILE_ELEMS + woff + 16 * BK);
        gload16(Bg + BK, Bs + TILE_ELEMS + woff);
        gload16(Bg + BK + 16 * (size_t)K,  Bs + TILE_ELEMS + woff + 16 * BK);
    }
    int bufc = 0;
    for (int t = 0; t < NT; ++t) {
        // own tile-t loads complete (4 newer stay in flight); barrier makes
        // every wave's tile-t staging visible before any ds_read.
        if (t + 1 < NT) asm volatile("s_waitcnt vmcnt(4)" ::: "memory");
        else            asm volatile("s_waitcnt vmcnt(0)" ::: "memory");
        __builtin_amdgcn_s_barrier();
        if (t + 2 < NT) {                      // prefetch tile t+2 (post-barrier: WAR-safe)
            int bn = bufc + 2; if (bn >= NBUF) bn -= NBUF;
            const size_t kb = (size_t)(t + 2) * BK;
            ushort_t* An = As + bn * TILE_ELEMS + woff;
            ushort_t* Bn = Bs + bn * TILE_ELEMS + woff;
            gload16(Ag + kb, An);
            gload16(Ag + kb + 16 * (size_t)lda, An + 16 * BK);
            gload16(Bg + kb, Bn);
            gload16(Bg + kb + 16 * (size_t)K,  Bn + 16 * BK);
        }
        const unsigned aaddr = a_lane + (unsigned)(bufc * BUF_BYTES);
        const unsigned baddr = b_lane + (unsigned)(bufc * BUF_BYTES);
        short8 af[4], bg[4];
#pragma unroll
        for (int i = 0; i < 4; i++)
            asm volatile("ds_read_b128 %0, %1 offset:%c2"
                         : "=v"(af[i]) : "v"(aaddr), "i"(i * 1024));
#pragma unroll
        for (int i = 0; i < 4; i++)
            asm volatile("ds_read_b128 %0, %1 offset:%c2"
                         : "=v"(bg[i]) : "v"(baddr), "i"(i * 1024));
        asm volatile("s_waitcnt lgkmcnt(0)" ::: "memory");
        __builtin_amdgcn_sched_barrier(0);
#pragma unroll
        for (int mi = 0; mi < 4; mi++)
#pragma unroll
            for (int ni = 0; ni < 4; ni++)
                g.acc[mi][ni] = __builtin_amdgcn_mfma_f32_16x16x32_bf16(
                    af[mi], bg[ni], g.acc[mi][ni], 0, 0, 0);
        bufc = bufc + 1 == NBUF ? 0 : bufc + 1;
    }
}

// out = silu(acc + bias), canonical bf16 out [M,N] (chunk-local, stride N)
__global__ __launch_bounds__(256)
void gemm_silu(const ushort_t* __restrict__ A, int lda,
               const ushort_t* __restrict__ Bt,
               const ushort_t* __restrict__ bias, ushort_t* __restrict__ out,
               int N, int K) {
    __shared__ __align__(16) ushort_t As[NBUF * TILE_ELEMS];
    __shared__ __align__(16) ushort_t Bs[NBUF * TILE_ELEMS];
    const int m0 = blockIdx.x * 128, n0 = blockIdx.y * 128;
    GemmCore g;
    gemm_core(g, A, lda, Bt, m0, n0, K, As, Bs);
#pragma unroll
    for (int mi = 0; mi < 4; mi++) {
        const int rbase = m0 + g.wm + mi * 16 + g.quad * 4;
#pragma unroll
        for (int ni = 0; ni < 4; ni++) {
            const int col = n0 + g.wn + ni * 16 + g.r16;
            const float bv = bf2f(bias[col]);
#pragma unroll
            for (int r = 0; r < 4; r++) {
                float v = g.acc[mi][ni][r] + bv;
                v = v / (1.0f + expf(-v));
                out[(size_t)(rbase + r) * N + col] = f2bf(v);
            }
        }
    }
}

// out = mask ? acc+bias+resid : resid  (writes d_out in detected dtype)
__global__ __launch_bounds__(256)
void gemm_out(const ushort_t* __restrict__ A, int lda,
              const ushort_t* __restrict__ Bt,
              const ushort_t* __restrict__ bias, void* __restrict__ out,
              const void* __restrict__ mask, const void* __restrict__ resid,
              int row0, int K, const int* __restrict__ flags) {
    __shared__ __align__(16) ushort_t As[NBUF * TILE_ELEMS];
    __shared__ __align__(16) ushort_t Bs[NBUF * TILE_ELEMS];
    const int flag = flags[0], flagM = flags[1];
    const int m0 = blockIdx.x * 128, n0 = blockIdx.y * 128;
    GemmCore g;
    gemm_core(g, A, lda, Bt, m0, n0, K, As, Bs);
#pragma unroll
    for (int mi = 0; mi < 4; mi++) {
        const int rbase = m0 + g.wm + mi * 16 + g.quad * 4;
#pragma unroll
        for (int ni = 0; ni < 4; ni++) {
            const int col = n0 + g.wn + ni * 16 + g.r16;
            const float bv = bf2f(bias[col]);
#pragma unroll
            for (int r = 0; r < 4; r++) {
                const size_t grow = (size_t)row0 + rbase + r;
                const float nd = loadany(resid, grow * FEAT_OUT + col, flag);
                const bool mk = maskany(mask, grow, flagM);
                float v = mk ? (g.acc[mi][ni][r] + bv + nd) : nd;
                if (flag) ((float*)out)[grow * FEAT_OUT + col] = v;
                else      ((ushort_t*)out)[grow * FEAT_OUT + col] = f2bf(v);
            }
        }
    }
}

// ---------- scores = hcat[.,1024:1280] @ aw2t[4,256]^T + ab2 ----------
__global__ __launch_bounds__(256)
void scores_kernel(const ushort_t* __restrict__ hcat,   // chunk-local [CH,1280]
                   const ushort_t* __restrict__ aw2t,
                   const ushort_t* __restrict__ ab2c,
                   float* __restrict__ scores, int row0) {
    const int row  = blockIdx.x * 4 + (threadIdx.x >> 6);
    const int lane = threadIdx.x & 63;
    float x[4];
    load4bf(hcat + (size_t)row * NCAT + 1024 + lane * 4, x);
    float acc[4];
#pragma unroll
    for (int h = 0; h < 4; h++) {
        float wv[4];
        load4bf(aw2t + h * 256 + lane * 4, wv);
        acc[h] = x[0]*wv[0] + x[1]*wv[1] + x[2]*wv[2] + x[3]*wv[3];
    }
#pragma unroll
    for (int m = 1; m < 64; m <<= 1)
#pragma unroll
        for (int h = 0; h < 4; h++) acc[h] += __shfl_xor(acc[h], m, 64);
    if (lane == 0) {
#pragma unroll
        for (int h = 0; h < 4; h++)
            scores[((size_t)row0 + row) * 4 + h] = acc[h] + bf2f(ab2c[h]);
    }
}

// ---------- masked softmax over the 256 nodes of each graph ----------
__global__ __launch_bounds__(256)
void softmax_kernel(const float* __restrict__ scores, const void* __restrict__ mask,
                    float* __restrict__ w, const int* __restrict__ flags) {
    const int flagM = flags[1];
    const int b = blockIdx.x, n = threadIdx.x;
    const int idx = b * 256 + n;
    float4 s = *(const float4*)(scores + (size_t)idx * 4);
    s.x *= 0.0625f; s.y *= 0.0625f; s.z *= 0.0625f; s.w *= 0.0625f;  // /sqrt(256)
    const bool mk = maskany(mask, idx, flagM);
    __shared__ float4 red[256];
    float4 v;
    v.x = mk ? s.x : -3.0e38f; v.y = mk ? s.y : -3.0e38f;
    v.z = mk ? s.z : -3.0e38f; v.w = mk ? s.w : -3.0e38f;
    red[n] = v; __syncthreads();
    for (int off = 128; off > 0; off >>= 1) {
        if (n < off) {
            float4 o = red[n + off], c = red[n];
            c.x = fmaxf(c.x, o.x); c.y = fmaxf(c.y, o.y);
            c.z = fmaxf(c.z, o.z); c.w = fmaxf(c.w, o.w);
            red[n] = c;
        }
        __syncthreads();
    }
    float4 mx = red[0]; __syncthreads();
    float4 e;
    e.x = mk ? expf(s.x - mx.x) : 0.f; e.y = mk ? expf(s.y - mx.y) : 0.f;
    e.z = mk ? expf(s.z - mx.z) : 0.f; e.w = mk ? expf(s.w - mx.w) : 0.f;
    red[n] = e; __syncthreads();
    for (int off = 128; off > 0; off >>= 1) {
        if (n < off) {
            float4 o = red[n + off], c = red[n];
            c.x += o.x; c.y += o.y; c.z += o.z; c.w += o.w;
            red[n] = c;
        }
        __syncthreads();
    }
    float4 sm = red[0];
    const float ix = (sm.x > 0.f) ? 1.f / sm.x : 0.f;
    const float iy = (sm.y > 0.f) ? 1.f / sm.y : 0.f;
    const float iz = (sm.z > 0.f) ? 1.f / sm.z : 0.f;
    const float iw = (sm.w > 0.f) ? 1.f / sm.w : 0.f;
    float4 r; r.x = e.x * ix; r.y = e.y * iy; r.z = e.z * iz; r.w = e.w * iw;
    *(float4*)(w + (size_t)idx * 4) = r;
}

// ---------- pooled[b][d] = sum_n new_nodes[b,n,d] * w[b,n,d>>6] ----------
__global__ __launch_bounds__(256)
void pooled_kernel(const void* __restrict__ dout, const float* __restrict__ w,
                   const int* __restrict__ flags) {
    const int flag = flags[0];
    const int b = blockIdx.x, t = threadIdx.x;
    __shared__ float wsh[1024];
    const float* wb = w + (size_t)b * 1024;
    for (int i = t; i < 1024; i += 256) wsh[i] = wb[i];
    __syncthreads();
    const int h = t >> 6;
    float acc = 0.f;
    const size_t base = (size_t)b * 65536;
    if (flag) {
        const float* nn = (const float*)dout + base;
#pragma unroll 4
        for (int n = 0; n < 256; n++) acc += nn[(size_t)n * 256 + t] * wsh[n * 4 + h];
        ((float*)dout)[(size_t)ROWS * 256 + (size_t)b * 256 + t] = acc;
    } else {
        const ushort_t* nn = (const ushort_t*)dout + base;
#pragma unroll 4
        for (int n = 0; n < 256; n++) acc += bf2f(nn[(size_t)n * 256 + t]) * wsh[n * 4 + h];
        ((ushort_t*)dout)[(size_t)ROWS * 256 + (size_t)b * 256 + t] = f2bf(acc);
    }
}

extern "C" void kernel_launch(void* const* d_in, const int* in_sizes, int n_in,
                              void* d_out, int out_size, void* d_ws, size_t ws_size,
                              hipStream_t stream) {
    (void)in_sizes; (void)n_in; (void)out_size;
    const void* nodes = d_in[0];
    const void* pe    = d_in[1];
    const void* mask  = d_in[2];
    const void* globs = d_in[3];
    const void* ln_g  = d_in[4];
    const void* ln_b  = d_in[5];
    const void* fw1   = d_in[6];
    const void* fb1   = d_in[7];
    const void* fw2   = d_in[8];
    const void* fb2   = d_in[9];
    const void* aw1   = d_in[10];
    const void* ab1   = d_in[11];
    const void* aw2   = d_in[12];
    const void* ab2   = d_in[13];

    // 16384-row chunks (~68 MB ws) when possible, else 8192 (~37 MB).
    const int CHR = (ws_size >= (size_t)80 * 1024 * 1024) ? 16384 : 8192;

    char* ws = (char*)d_ws;
    size_t o = 0;
    auto take = [&](size_t bytes) -> char* {
        char* p = ws + o;
        o += (bytes + 255) & ~(size_t)255;
        return p;
    };
    ushort_t* inp  = (ushort_t*)take((size_t)CHR * IN_D * 2);
    ushort_t* hcat = (ushort_t*)take((size_t)CHR * NCAT * 2);
    float*    sc   = (float*)   take((size_t)ROWS * 4 * 4);
    float*    wsm  = (float*)   take((size_t)ROWS * 4 * 4);
    ushort_t* w1cat= (ushort_t*)take((size_t)NCAT * 576 * 2);
    ushort_t* fw2t = (ushort_t*)take(1024 * 256 * 2);
    ushort_t* aw2t = (ushort_t*)take(256 * 4 * 2);
    ushort_t* gcan = (ushort_t*)take(32768 * 2);
    ushort_t* lgc  = (ushort_t*)take(512 * 2);
    ushort_t* lbc  = (ushort_t*)take(512 * 2);
    ushort_t* bcat = (ushort_t*)take((size_t)NCAT * 2);
    ushort_t* fb2c = (ushort_t*)take(256 * 2);
    ushort_t* ab2c = (ushort_t*)take(4 * 2);
    int*      flags= (int*)     take(64);

    detect_kernel<<<1, 256, 0, stream>>>(nodes, mask, flags);
    convert_all<<<139, 256, 0, stream>>>(globs, ln_g, ln_b, fb1, fb2, ab1, ab2,
                                         gcan, lgc, lbc, bcat, fb2c, ab2c, flags);
    transpose_all<<<3908, 256, 0, stream>>>(fw1, fw2, aw1, aw2,
                                            w1cat, fw2t, aw2t, flags);

    const int nchunk = ROWS / CHR;
    for (int c = 0; c < nchunk; c++) {
        const int row0 = c * CHR;
        ln_concat_kernel<<<CHR / 4, 256, 0, stream>>>(nodes, pe, gcan, lgc, lbc,
                                                      inp, row0, flags);
        gemm_silu<<<dim3(CHR / 128, NCAT / 128), 256, 0, stream>>>(
            inp, IN_D, w1cat, bcat, hcat, NCAT, IN_D);
        scores_kernel<<<CHR / 4, 256, 0, stream>>>(hcat, aw2t, ab2c, sc, row0);
        gemm_out<<<dim3(CHR / 128, FEAT_OUT / 128), 256, 0, stream>>>(
            hcat, NCAT, fw2t, fb2c, d_out, mask, nodes, row0, FEAT_HID, flags);
    }

    softmax_kernel<<<B_GRAPH, 256, 0, stream>>>(sc, mask, wsm, flags);
    pooled_kernel<<<B_GRAPH, 256, 0, stream>>>(d_out, wsm, flags);
}

// Round 3
// 967.957 us; speedup vs baseline: 2.0014x; 1.0909x over previous
//
#include <hip/hip_runtime.h>
#include <cmath>

typedef unsigned short ushort_t;
typedef unsigned char uchar_t;
typedef short short8 __attribute__((ext_vector_type(8)));
typedef float floatx4 __attribute__((ext_vector_type(4)));

#define B_GRAPH 512
#define ROWS 131072
#define IN_D 576                   // 512 LN'd feats + 64 ctx
#define FEAT_HID 1024
#define ATTN_HID 256
#define NCAT 1280                  // fused feat1(1024) + attn1(256) output cols
#define FEAT_OUT 256
#define BK 32                      // K-step; LDS row = 32 bf16 = 64B (linear)
#define NBUF 3                     // depth-2 prefetch pipeline
#define A_TILE (128 * BK)          // 4096 ushorts (8 KB)
#define B_TILE (256 * BK)          // 8192 ushorts (16 KB)

// ---------- bf16 helpers (bit-level) ----------
__device__ __forceinline__ float bf2f(ushort_t h) {
    return __uint_as_float(((unsigned int)h) << 16);
}
__device__ __forceinline__ ushort_t f2bf(float f) {
    unsigned int u = __float_as_uint(f);
    u += 0x7fffu + ((u >> 16) & 1u);   // RNE
    return (ushort_t)(u >> 16);
}
__device__ __forceinline__ void load4bf(const ushort_t* p, float f[4]) {
    uint2 u = *(const uint2*)p;
    f[0] = __uint_as_float(u.x << 16);
    f[1] = __uint_as_float(u.x & 0xffff0000u);
    f[2] = __uint_as_float(u.y << 16);
    f[3] = __uint_as_float(u.y & 0xffff0000u);
}

// ---------- runtime dtype detection ----------
__global__ void detect_kernel(const void* nodes, const void* maskp, int* flags) {
    const int t = threadIdx.x;
    const ushort_t* nb = (const ushort_t*)nodes;
    int cnt = 0;
    for (int i = t; i < 4096; i += 256) {
        unsigned e = ((unsigned)nb[i] >> 7) & 0xffu;
        if (e >= 147u) cnt++;
    }
    const unsigned* mw = (const unsigned*)maskp;
    int mcnt = 0;
    for (int i = t; i < 16384; i += 256) {
        if (mw[i] > 1u) mcnt++;
    }
    __shared__ int r1[256], r2[256];
    r1[t] = cnt; r2[t] = mcnt; __syncthreads();
    for (int off = 128; off > 0; off >>= 1) {
        if (t < off) { r1[t] += r1[t + off]; r2[t] += r2[t + off]; }
        __syncthreads();
    }
    if (t == 0) { flags[0] = (r1[0] > 64) ? 1 : 0; flags[1] = (r2[0] > 16) ? 1 : 0; }
}

__device__ __forceinline__ float loadany(const void* p, size_t i, int flag) {
    return flag ? ((const float*)p)[i] : bf2f(((const ushort_t*)p)[i]);
}
__device__ __forceinline__ bool maskany(const void* p, size_t i, int flagM) {
    return flagM ? (((const uchar_t*)p)[i] != 0) : (((const int*)p)[i] != 0);
}

// ---------- merged small-tensor convert -> canonical bf16 ----------
__global__ __launch_bounds__(256)
void convert_all(const void* globs, const void* lng, const void* lnb,
                 const void* fb1, const void* fb2, const void* ab1, const void* ab2,
                 ushort_t* gcan, ushort_t* lgc, ushort_t* lbc,
                 ushort_t* bcat, ushort_t* fb2c, ushort_t* ab2c,
                 const int* flags) {
    const int flag = flags[0];
    int i = blockIdx.x * 256 + threadIdx.x;
    if (i < 32768) { gcan[i] = f2bf(loadany(globs, i, flag)); return; }
    i -= 32768;
    if (i < 512)   { lgc[i]  = f2bf(loadany(lng,   i, flag)); return; }
    i -= 512;
    if (i < 512)   { lbc[i]  = f2bf(loadany(lnb,   i, flag)); return; }
    i -= 512;
    if (i < 1024)  { bcat[i] = f2bf(loadany(fb1,   i, flag)); return; }
    i -= 1024;
    if (i < 256)   { bcat[1024 + i] = f2bf(loadany(ab1, i, flag)); return; }
    i -= 256;
    if (i < 256)   { fb2c[i] = f2bf(loadany(fb2,   i, flag)); return; }
    i -= 256;
    if (i < 4)     { ab2c[i] = f2bf(loadany(ab2,   i, flag)); }
}

// ---------- merged weight transposes -> canonical bf16 [C,R] ----------
__global__ __launch_bounds__(256)
void transpose_all(const void* fw1, const void* fw2, const void* aw1, const void* aw2,
                   ushort_t* w1cat, ushort_t* fw2t, ushort_t* aw2t,
                   const int* flags) {
    const int flag = flags[0];
    int i = blockIdx.x * 256 + threadIdx.x;
    if (i < 576 * 1024) {
        int r = i >> 10, c = i & 1023;
        w1cat[(size_t)c * 576 + r] = f2bf(loadany(fw1, i, flag)); return;
    }
    i -= 576 * 1024;
    if (i < 1024 * 256) {
        int r = i >> 8, c = i & 255;
        fw2t[(size_t)c * 1024 + r] = f2bf(loadany(fw2, i, flag)); return;
    }
    i -= 1024 * 256;
    if (i < 576 * 256) {
        int r = i >> 8, c = i & 255;
        w1cat[(size_t)(1024 + c) * 576 + r] = f2bf(loadany(aw1, i, flag)); return;
    }
    i -= 576 * 256;
    if (i < 256 * 4) {
        int r = i >> 2, c = i & 3;
        aw2t[(size_t)c * 256 + r] = f2bf(loadany(aw2, i, flag));
    }
}

// ---------- LN over 512 + concat canonical ctx -> inp[CH][576] bf16 ----------
__global__ __launch_bounds__(256)
void ln_concat_kernel(const void* __restrict__ nodes, const void* __restrict__ pe,
                      const ushort_t* __restrict__ gcan,
                      const ushort_t* __restrict__ lg, const ushort_t* __restrict__ lb,
                      ushort_t* __restrict__ inp, int row0, const int* __restrict__ flags) {
    const int flag = flags[0];
    const int row  = blockIdx.x * 4 + (threadIdx.x >> 6);
    const int lane = threadIdx.x & 63;
    const size_t grow = (size_t)row0 + row;
    float xa[4], xb[4];
    if (flag) {
        float4 a = *(const float4*)((const float*)nodes + grow * 256 + lane * 4);
        float4 b = *(const float4*)((const float*)pe    + grow * 256 + lane * 4);
        xa[0]=a.x; xa[1]=a.y; xa[2]=a.z; xa[3]=a.w;
        xb[0]=b.x; xb[1]=b.y; xb[2]=b.z; xb[3]=b.w;
    } else {
        load4bf((const ushort_t*)nodes + grow * 256 + lane * 4, xa);
        load4bf((const ushort_t*)pe    + grow * 256 + lane * 4, xb);
    }
    float s = 0.f, q = 0.f;
#pragma unroll
    for (int j = 0; j < 4; j++) { s += xa[j] + xb[j]; q += xa[j]*xa[j] + xb[j]*xb[j]; }
#pragma unroll
    for (int m = 1; m < 64; m <<= 1) { s += __shfl_xor(s, m, 64); q += __shfl_xor(q, m, 64); }
    const float mu   = s * (1.0f / 512.0f);
    const float var  = q * (1.0f / 512.0f) - mu * mu;
    const float rstd = rsqrtf(fmaxf(var, 0.f) + 1e-5f);
    float ga[4], gb[4], ba[4], bb[4];
    load4bf(lg + lane * 4, ga);  load4bf(lg + 256 + lane * 4, gb);
    load4bf(lb + lane * 4, ba);  load4bf(lb + 256 + lane * 4, bb);
    ushort_t r0[4], r1[4];
#pragma unroll
    for (int j = 0; j < 4; j++) {
        r0[j] = f2bf((xa[j] - mu) * rstd * ga[j] + ba[j]);
        r1[j] = f2bf((xb[j] - mu) * rstd * gb[j] + bb[j]);
    }
    ushort_t* op = inp + (size_t)row * IN_D;
    uint2 p0, p1;
    p0.x = (unsigned)r0[0] | ((unsigned)r0[1] << 16);
    p0.y = (unsigned)r0[2] | ((unsigned)r0[3] << 16);
    p1.x = (unsigned)r1[0] | ((unsigned)r1[1] << 16);
    p1.y = (unsigned)r1[2] | ((unsigned)r1[3] << 16);
    *(uint2*)(op + lane * 4)       = p0;
    *(uint2*)(op + 256 + lane * 4) = p1;
    op[512 + lane] = gcan[(grow >> 8) * 64 + lane];
}

// ---------- pipelined MFMA GEMM core, block 128x256, wave-tile 128x64 ----------
// A[M,*] row-stride lda, Bt[N,K] rm. 4 waves side-by-side in N (wn = wave*64);
// every wave spans all 128 M-rows -> acc[8][4], 32 MFMA per 12 ds_read_b128
// (compute:LDS ratio 2.67 vs 2.0 for 64x64). Depth-2 prefetch, 3 buffers
// (A 24KB + B 48KB = 72KB -> 2 blocks/CU). Counted s_waitcnt vmcnt(6)
// (6 gload16/wave/tile), raw s_barrier, inline-asm ds_read_b128 +
// lgkmcnt(0) + sched_barrier(0) (rule 18).
struct GemmCore {
    floatx4 acc[8][4];
    int wn, r16, quad;
};

__device__ __forceinline__ void gload16(const ushort_t* g, ushort_t* l) {
    __builtin_amdgcn_global_load_lds(
        (const __attribute__((address_space(1))) unsigned int*)g,
        (__attribute__((address_space(3))) unsigned int*)l, 16, 0, 0);
}
__device__ __forceinline__ unsigned lds_off(const void* p) {
    return (unsigned)(size_t)(const __attribute__((address_space(3))) char*)p;
}

__device__ __forceinline__ void gemm_core(GemmCore& g,
        const ushort_t* __restrict__ A, int lda, const ushort_t* __restrict__ Bt,
        int m0, int n0, int K, ushort_t* As, ushort_t* Bs) {
    const int tid = threadIdx.x;
    const int wave = tid >> 6, lane = tid & 63;
    g.wn = wave * 64; g.r16 = lane & 15; g.quad = lane >> 4;
#pragma unroll
    for (int i = 0; i < 8; i++)
#pragma unroll
        for (int j = 0; j < 4; j++) g.acc[i][j] = (floatx4){0.f, 0.f, 0.f, 0.f};

    // staging: wave w -> A rows [w*32, w*32+32) (2 insts), B rows [w*64, w*64+64) (4 insts)
    const int sr   = lane >> 2;          // 0..15
    const int scol = (lane & 3) * 8;
    const ushort_t* Ag = A  + (size_t)(m0 + wave * 32 + sr) * lda + scol;
    const ushort_t* Bg = Bt + (size_t)(n0 + wave * 64 + sr) * K  + scol;
    ushort_t* Asw = As + wave * 32 * BK;
    ushort_t* Bsw = Bs + wave * 64 * BK;

    const unsigned a_lane = lds_off(As) + (unsigned)((g.r16 * BK + g.quad * 8) * 2);
    const unsigned b_lane = lds_off(Bs) + (unsigned)(((g.wn + g.r16) * BK + g.quad * 8) * 2);

    const int NT = K / BK;
#define STAGE_TILE(T, BUF) do {                                        \
        const size_t kb = (size_t)(T) * BK;                            \
        ushort_t* Ad = Asw + (BUF) * A_TILE;                           \
        ushort_t* Bd = Bsw + (BUF) * B_TILE;                           \
        gload16(Ag + kb,                    Ad);                       \
        gload16(Ag + kb + 16 * (size_t)lda, Ad + 16 * BK);             \
        gload16(Bg + kb,                    Bd);                       \
        gload16(Bg + kb + 16 * (size_t)K,   Bd + 16 * BK);             \
        gload16(Bg + kb + 32 * (size_t)K,   Bd + 32 * BK);             \
        gload16(Bg + kb + 48 * (size_t)K,   Bd + 48 * BK);             \
    } while (0)

    STAGE_TILE(0, 0);
    if (NT > 1) STAGE_TILE(1, 1);

    int bufc = 0;
    for (int t = 0; t < NT; ++t) {
        if (t + 1 < NT) asm volatile("s_waitcnt vmcnt(6)" ::: "memory");
        else            asm volatile("s_waitcnt vmcnt(0)" ::: "memory");
        __builtin_amdgcn_s_barrier();
        __builtin_amdgcn_sched_barrier(0);
        if (t + 2 < NT) {                      // prefetch tile t+2 (post-barrier: WAR-safe)
            int bn = bufc + 2; if (bn >= NBUF) bn -= NBUF;
            STAGE_TILE(t + 2, bn);
        }
        const unsigned aaddr = a_lane + (unsigned)(bufc * (A_TILE * 2));
        const unsigned baddr = b_lane + (unsigned)(bufc * (B_TILE * 2));
        short8 af[8], bg[4];
#pragma unroll
        for (int i = 0; i < 8; i++)
            asm volatile("ds_read_b128 %0, %1 offset:%c2"
                         : "=v"(af[i]) : "v"(aaddr), "i"(i * 1024));
#pragma unroll
        for (int i = 0; i < 4; i++)
            asm volatile("ds_read_b128 %0, %1 offset:%c2"
                         : "=v"(bg[i]) : "v"(baddr), "i"(i * 1024));
        asm volatile("s_waitcnt lgkmcnt(0)" ::: "memory");
        __builtin_amdgcn_sched_barrier(0);
#pragma unroll
        for (int mi = 0; mi < 8; mi++)
#pragma unroll
            for (int ni = 0; ni < 4; ni++)
                g.acc[mi][ni] = __builtin_amdgcn_mfma_f32_16x16x32_bf16(
                    af[mi], bg[ni], g.acc[mi][ni], 0, 0, 0);
        bufc = bufc + 1 == NBUF ? 0 : bufc + 1;
    }
#undef STAGE_TILE
}

// out = silu(acc + bias), canonical bf16 out [M,N] (chunk-local, stride N)
__global__ __launch_bounds__(256, 2)
void gemm_silu(const ushort_t* __restrict__ A, int lda,
               const ushort_t* __restrict__ Bt,
               const ushort_t* __restrict__ bias, ushort_t* __restrict__ out,
               int N, int K) {
    __shared__ __align__(16) ushort_t As[NBUF * A_TILE];
    __shared__ __align__(16) ushort_t Bs[NBUF * B_TILE];
    const int m0 = blockIdx.x * 128, n0 = blockIdx.y * 256;
    GemmCore g;
    gemm_core(g, A, lda, Bt, m0, n0, K, As, Bs);
#pragma unroll
    for (int mi = 0; mi < 8; mi++) {
        const int rbase = m0 + mi * 16 + g.quad * 4;
#pragma unroll
        for (int ni = 0; ni < 4; ni++) {
            const int col = n0 + g.wn + ni * 16 + g.r16;
            const float bv = bf2f(bias[col]);
#pragma unroll
            for (int r = 0; r < 4; r++) {
                float v = g.acc[mi][ni][r] + bv;
                v = v / (1.0f + expf(-v));
                out[(size_t)(rbase + r) * N + col] = f2bf(v);
            }
        }
    }
}

// out = mask ? acc+bias+resid : resid  (writes d_out in detected dtype)
__global__ __launch_bounds__(256, 2)
void gemm_out(const ushort_t* __restrict__ A, int lda,
              const ushort_t* __restrict__ Bt,
              const ushort_t* __restrict__ bias, void* __restrict__ out,
              const void* __restrict__ mask, const void* __restrict__ resid,
              int row0, int K, const int* __restrict__ flags) {
    __shared__ __align__(16) ushort_t As[NBUF * A_TILE];
    __shared__ __align__(16) ushort_t Bs[NBUF * B_TILE];
    const int flag = flags[0], flagM = flags[1];
    const int m0 = blockIdx.x * 128, n0 = blockIdx.y * 256;
    GemmCore g;
    gemm_core(g, A, lda, Bt, m0, n0, K, As, Bs);
#pragma unroll
    for (int mi = 0; mi < 8; mi++) {
        const int rbase = m0 + mi * 16 + g.quad * 4;
#pragma unroll
        for (int ni = 0; ni < 4; ni++) {
            const int col = n0 + g.wn + ni * 16 + g.r16;
            const float bv = bf2f(bias[col]);
#pragma unroll
            for (int r = 0; r < 4; r++) {
                const size_t grow = (size_t)row0 + rbase + r;
                const float nd = loadany(resid, grow * FEAT_OUT + col, flag);
                const bool mk = maskany(mask, grow, flagM);
                float v = mk ? (g.acc[mi][ni][r] + bv + nd) : nd;
                if (flag) ((float*)out)[grow * FEAT_OUT + col] = v;
                else      ((ushort_t*)out)[grow * FEAT_OUT + col] = f2bf(v);
            }
        }
    }
}

// ---------- scores = hcat[.,1024:1280] @ aw2t[4,256]^T + ab2 ----------
__global__ __launch_bounds__(256)
void scores_kernel(const ushort_t* __restrict__ hcat,   // chunk-local [CH,1280]
                   const ushort_t* __restrict__ aw2t,
                   const ushort_t* __restrict__ ab2c,
                   float* __restrict__ scores, int row0) {
    const int row  = blockIdx.x * 4 + (threadIdx.x >> 6);
    const int lane = threadIdx.x & 63;
    float x[4];
    load4bf(hcat + (size_t)row * NCAT + 1024 + lane * 4, x);
    float acc[4];
#pragma unroll
    for (int h = 0; h < 4; h++) {
        float wv[4];
        load4bf(aw2t + h * 256 + lane * 4, wv);
        acc[h] = x[0]*wv[0] + x[1]*wv[1] + x[2]*wv[2] + x[3]*wv[3];
    }
#pragma unroll
    for (int m = 1; m < 64; m <<= 1)
#pragma unroll
        for (int h = 0; h < 4; h++) acc[h] += __shfl_xor(acc[h], m, 64);
    if (lane == 0) {
#pragma unroll
        for (int h = 0; h < 4; h++)
            scores[((size_t)row0 + row) * 4 + h] = acc[h] + bf2f(ab2c[h]);
    }
}

// ---------- masked softmax over the 256 nodes of each graph ----------
__global__ __launch_bounds__(256)
void softmax_kernel(const float* __restrict__ scores, const void* __restrict__ mask,
                    float* __restrict__ w, const int* __restrict__ flags) {
    const int flagM = flags[1];
    const int b = blockIdx.x, n = threadIdx.x;
    const int idx = b * 256 + n;
    float4 s = *(const float4*)(scores + (size_t)idx * 4);
    s.x *= 0.0625f; s.y *= 0.0625f; s.z *= 0.0625f; s.w *= 0.0625f;  // /sqrt(256)
    const bool mk = maskany(mask, idx, flagM);
    __shared__ float4 red[256];
    float4 v;
    v.x = mk ? s.x : -3.0e38f; v.y = mk ? s.y : -3.0e38f;
    v.z = mk ? s.z : -3.0e38f; v.w = mk ? s.w : -3.0e38f;
    red[n] = v; __syncthreads();
    for (int off = 128; off > 0; off >>= 1) {
        if (n < off) {
            float4 o = red[n + off], c = red[n];
            c.x = fmaxf(c.x, o.x); c.y = fmaxf(c.y, o.y);
            c.z = fmaxf(c.z, o.z); c.w = fmaxf(c.w, o.w);
            red[n] = c;
        }
        __syncthreads();
    }
    float4 mx = red[0]; __syncthreads();
    float4 e;
    e.x = mk ? expf(s.x - mx.x) : 0.f; e.y = mk ? expf(s.y - mx.y) : 0.f;
    e.z = mk ? expf(s.z - mx.z) : 0.f; e.w = mk ? expf(s.w - mx.w) : 0.f;
    red[n] = e; __syncthreads();
    for (int off = 128; off > 0; off >>= 1) {
        if (n < off) {
            float4 o = red[n + off], c = red[n];
            c.x += o.x; c.y += o.y; c.z += o.z; c.w += o.w;
            red[n] = c;
        }
        __syncthreads();
    }
    float4 sm = red[0];
    const float ix = (sm.x > 0.f) ? 1.f / sm.x : 0.f;
    const float iy = (sm.y > 0.f) ? 1.f / sm.y : 0.f;
    const float iz = (sm.z > 0.f) ? 1.f / sm.z : 0.f;
    const float iw = (sm.w > 0.f) ? 1.f / sm.w : 0.f;
    float4 r; r.x = e.x * ix; r.y = e.y * iy; r.z = e.z * iz; r.w = e.w * iw;
    *(float4*)(w + (size_t)idx * 4) = r;
}

// ---------- pooled[b][d] = sum_n new_nodes[b,n,d] * w[b,n,d>>6] ----------
__global__ __launch_bounds__(256)
void pooled_kernel(const void* __restrict__ dout, const float* __restrict__ w,
                   const int* __restrict__ flags) {
    const int flag = flags[0];
    const int b = blockIdx.x, t = threadIdx.x;
    __shared__ float wsh[1024];
    const float* wb = w + (size_t)b * 1024;
    for (int i = t; i < 1024; i += 256) wsh[i] = wb[i];
    __syncthreads();
    const int h = t >> 6;
    float acc = 0.f;
    const size_t base = (size_t)b * 65536;
    if (flag) {
        const float* nn = (const float*)dout + base;
#pragma unroll 4
        for (int n = 0; n < 256; n++) acc += nn[(size_t)n * 256 + t] * wsh[n * 4 + h];
        ((float*)dout)[(size_t)ROWS * 256 + (size_t)b * 256 + t] = acc;
    } else {
        const ushort_t* nn = (const ushort_t*)dout + base;
#pragma unroll 4
        for (int n = 0; n < 256; n++) acc += bf2f(nn[(size_t)n * 256 + t]) * wsh[n * 4 + h];
        ((ushort_t*)dout)[(size_t)ROWS * 256 + (size_t)b * 256 + t] = f2bf(acc);
    }
}

extern "C" void kernel_launch(void* const* d_in, const int* in_sizes, int n_in,
                              void* d_out, int out_size, void* d_ws, size_t ws_size,
                              hipStream_t stream) {
    (void)in_sizes; (void)n_in; (void)out_size;
    const void* nodes = d_in[0];
    const void* pe    = d_in[1];
    const void* mask  = d_in[2];
    const void* globs = d_in[3];
    const void* ln_g  = d_in[4];
    const void* ln_b  = d_in[5];
    const void* fw1   = d_in[6];
    const void* fb1   = d_in[7];
    const void* fw2   = d_in[8];
    const void* fb2   = d_in[9];
    const void* aw1   = d_in[10];
    const void* ab1   = d_in[11];
    const void* aw2   = d_in[12];
    const void* ab2   = d_in[13];

    // chunk rows: pick largest that fits the workspace; hcat chunk stays
    // L3-resident (<= 84 MB at 32768) so the h round-trip costs no HBM.
    int CHR;
    if      (ws_size >= (size_t)140 * 1024 * 1024) CHR = 32768;
    else if (ws_size >= (size_t)80  * 1024 * 1024) CHR = 16384;
    else                                           CHR = 8192;

    char* ws = (char*)d_ws;
    size_t o = 0;
    auto take = [&](size_t bytes) -> char* {
        char* p = ws + o;
        o += (bytes + 255) & ~(size_t)255;
        return p;
    };
    ushort_t* inp  = (ushort_t*)take((size_t)CHR * IN_D * 2);
    ushort_t* hcat = (ushort_t*)take((size_t)CHR * NCAT * 2);
    float*    sc   = (float*)   take((size_t)ROWS * 4 * 4);
    float*    wsm  = (float*)   take((size_t)ROWS * 4 * 4);
    ushort_t* w1cat= (ushort_t*)take((size_t)NCAT * 576 * 2);
    ushort_t* fw2t = (ushort_t*)take(1024 * 256 * 2);
    ushort_t* aw2t = (ushort_t*)take(256 * 4 * 2);
    ushort_t* gcan = (ushort_t*)take(32768 * 2);
    ushort_t* lgc  = (ushort_t*)take(512 * 2);
    ushort_t* lbc  = (ushort_t*)take(512 * 2);
    ushort_t* bcat = (ushort_t*)take((size_t)NCAT * 2);
    ushort_t* fb2c = (ushort_t*)take(256 * 2);
    ushort_t* ab2c = (ushort_t*)take(4 * 2);
    int*      flags= (int*)     take(64);

    detect_kernel<<<1, 256, 0, stream>>>(nodes, mask, flags);
    convert_all<<<139, 256, 0, stream>>>(globs, ln_g, ln_b, fb1, fb2, ab1, ab2,
                                         gcan, lgc, lbc, bcat, fb2c, ab2c, flags);
    transpose_all<<<3908, 256, 0, stream>>>(fw1, fw2, aw1, aw2,
                                            w1cat, fw2t, aw2t, flags);

    const int nchunk = ROWS / CHR;
    for (int c = 0; c < nchunk; c++) {
        const int row0 = c * CHR;
        ln_concat_kernel<<<CHR / 4, 256, 0, stream>>>(nodes, pe, gcan, lgc, lbc,
                                                      inp, row0, flags);
        gemm_silu<<<dim3(CHR / 128, NCAT / 256), 256, 0, stream>>>(
            inp, IN_D, w1cat, bcat, hcat, NCAT, IN_D);
        scores_kernel<<<CHR / 4, 256, 0, stream>>>(hcat, aw2t, ab2c, sc, row0);
        gemm_out<<<dim3(CHR / 128, FEAT_OUT / 256), 256, 0, stream>>>(
            hcat, NCAT, fw2t, fb2c, d_out, mask, nodes, row0, FEAT_HID, flags);
    }

    softmax_kernel<<<B_GRAPH, 256, 0, stream>>>(sc, mask, wsm, flags);
    pooled_kernel<<<B_GRAPH, 256, 0, stream>>>(d_out, wsm, flags);
}

// Round 4
// 869.314 us; speedup vs baseline: 2.2285x; 1.1135x over previous
//
#include <hip/hip_runtime.h>
#include <cmath>

typedef unsigned short ushort_t;
typedef unsigned char uchar_t;
typedef short short8 __attribute__((ext_vector_type(8)));
typedef float floatx4 __attribute__((ext_vector_type(4)));

#define B_GRAPH 512
#define ROWS 131072
#define IN_D 576                   // 512 LN'd feats + 64 ctx
#define FEAT_HID 1024
#define ATTN_HID 256
#define NCAT 1280                  // fused feat1(1024) + attn1(256) output cols
#define FEAT_OUT 256
#define BK 32                      // K-step; LDS row = 32 bf16 = 64B (linear)
#define NBUF 3                     // depth-2 prefetch pipeline

// ---------- bf16 helpers (bit-level) ----------
__device__ __forceinline__ float bf2f(ushort_t h) {
    return __uint_as_float(((unsigned int)h) << 16);
}
__device__ __forceinline__ ushort_t f2bf(float f) {
    unsigned int u = __float_as_uint(f);
    u += 0x7fffu + ((u >> 16) & 1u);   // RNE
    return (ushort_t)(u >> 16);
}
__device__ __forceinline__ void load4bf(const ushort_t* p, float f[4]) {
    uint2 u = *(const uint2*)p;
    f[0] = __uint_as_float(u.x << 16);
    f[1] = __uint_as_float(u.x & 0xffff0000u);
    f[2] = __uint_as_float(u.y << 16);
    f[3] = __uint_as_float(u.y & 0xffff0000u);
}
// packed RNE f32x2 -> bf16x2 (gfx950 v_cvt_pk_bf16_f32; T12, HW-verified)
__device__ __forceinline__ unsigned cvtpk_bf16(float lo, float hi) {
    unsigned r;
    asm("v_cvt_pk_bf16_f32 %0, %1, %2" : "=v"(r) : "v"(lo), "v"(hi));
    return r;
}
__device__ __forceinline__ float silu_fast(float v) {
    // v * sigmoid(v); v_exp_f32 + v_rcp_f32 (err << bf16 quantum)
    const float e = __expf(-v);
    return v * __builtin_amdgcn_rcpf(1.0f + e);
}

// ---------- runtime dtype detection ----------
__global__ void detect_kernel(const void* nodes, const void* maskp, int* flags) {
    const int t = threadIdx.x;
    const ushort_t* nb = (const ushort_t*)nodes;
    int cnt = 0;
    for (int i = t; i < 4096; i += 256) {
        unsigned e = ((unsigned)nb[i] >> 7) & 0xffu;
        if (e >= 147u) cnt++;
    }
    const unsigned* mw = (const unsigned*)maskp;
    int mcnt = 0;
    for (int i = t; i < 16384; i += 256) {
        if (mw[i] > 1u) mcnt++;
    }
    __shared__ int r1[256], r2[256];
    r1[t] = cnt; r2[t] = mcnt; __syncthreads();
    for (int off = 128; off > 0; off >>= 1) {
        if (t < off) { r1[t] += r1[t + off]; r2[t] += r2[t + off]; }
        __syncthreads();
    }
    if (t == 0) { flags[0] = (r1[0] > 64) ? 1 : 0; flags[1] = (r2[0] > 16) ? 1 : 0; }
}

__device__ __forceinline__ float loadany(const void* p, size_t i, int flag) {
    return flag ? ((const float*)p)[i] : bf2f(((const ushort_t*)p)[i]);
}
__device__ __forceinline__ bool maskany(const void* p, size_t i, int flagM) {
    return flagM ? (((const uchar_t*)p)[i] != 0) : (((const int*)p)[i] != 0);
}

// ---------- merged small-tensor convert -> canonical bf16 ----------
__global__ __launch_bounds__(256)
void convert_all(const void* globs, const void* lng, const void* lnb,
                 const void* fb1, const void* fb2, const void* ab1, const void* ab2,
                 ushort_t* gcan, ushort_t* lgc, ushort_t* lbc,
                 ushort_t* bcat, ushort_t* fb2c, ushort_t* ab2c,
                 const int* flags) {
    const int flag = flags[0];
    int i = blockIdx.x * 256 + threadIdx.x;
    if (i < 32768) { gcan[i] = f2bf(loadany(globs, i, flag)); return; }
    i -= 32768;
    if (i < 512)   { lgc[i]  = f2bf(loadany(lng,   i, flag)); return; }
    i -= 512;
    if (i < 512)   { lbc[i]  = f2bf(loadany(lnb,   i, flag)); return; }
    i -= 512;
    if (i < 1024)  { bcat[i] = f2bf(loadany(fb1,   i, flag)); return; }
    i -= 1024;
    if (i < 256)   { bcat[1024 + i] = f2bf(loadany(ab1, i, flag)); return; }
    i -= 256;
    if (i < 256)   { fb2c[i] = f2bf(loadany(fb2,   i, flag)); return; }
    i -= 256;
    if (i < 4)     { ab2c[i] = f2bf(loadany(ab2,   i, flag)); }
}

// ---------- merged weight transposes -> canonical bf16 [C,R] ----------
__global__ __launch_bounds__(256)
void transpose_all(const void* fw1, const void* fw2, const void* aw1, const void* aw2,
                   ushort_t* w1cat, ushort_t* fw2t, ushort_t* aw2t,
                   const int* flags) {
    const int flag = flags[0];
    int i = blockIdx.x * 256 + threadIdx.x;
    if (i < 576 * 1024) {
        int r = i >> 10, c = i & 1023;
        w1cat[(size_t)c * 576 + r] = f2bf(loadany(fw1, i, flag)); return;
    }
    i -= 576 * 1024;
    if (i < 1024 * 256) {
        int r = i >> 8, c = i & 255;
        fw2t[(size_t)c * 1024 + r] = f2bf(loadany(fw2, i, flag)); return;
    }
    i -= 1024 * 256;
    if (i < 576 * 256) {
        int r = i >> 8, c = i & 255;
        w1cat[(size_t)(1024 + c) * 576 + r] = f2bf(loadany(aw1, i, flag)); return;
    }
    i -= 576 * 256;
    if (i < 256 * 4) {
        int r = i >> 2, c = i & 3;
        aw2t[(size_t)c * 256 + r] = f2bf(loadany(aw2, i, flag));
    }
}

// ---------- LN over 512 + concat canonical ctx -> inp[CH][576] bf16 ----------
__global__ __launch_bounds__(256)
void ln_concat_kernel(const void* __restrict__ nodes, const void* __restrict__ pe,
                      const ushort_t* __restrict__ gcan,
                      const ushort_t* __restrict__ lg, const ushort_t* __restrict__ lb,
                      ushort_t* __restrict__ inp, int row0, const int* __restrict__ flags) {
    const int flag = flags[0];
    const int row  = blockIdx.x * 4 + (threadIdx.x >> 6);
    const int lane = threadIdx.x & 63;
    const size_t grow = (size_t)row0 + row;
    float xa[4], xb[4];
    if (flag) {
        float4 a = *(const float4*)((const float*)nodes + grow * 256 + lane * 4);
        float4 b = *(const float4*)((const float*)pe    + grow * 256 + lane * 4);
        xa[0]=a.x; xa[1]=a.y; xa[2]=a.z; xa[3]=a.w;
        xb[0]=b.x; xb[1]=b.y; xb[2]=b.z; xb[3]=b.w;
    } else {
        load4bf((const ushort_t*)nodes + grow * 256 + lane * 4, xa);
        load4bf((const ushort_t*)pe    + grow * 256 + lane * 4, xb);
    }
    float s = 0.f, q = 0.f;
#pragma unroll
    for (int j = 0; j < 4; j++) { s += xa[j] + xb[j]; q += xa[j]*xa[j] + xb[j]*xb[j]; }
#pragma unroll
    for (int m = 1; m < 64; m <<= 1) { s += __shfl_xor(s, m, 64); q += __shfl_xor(q, m, 64); }
    const float mu   = s * (1.0f / 512.0f);
    const float var  = q * (1.0f / 512.0f) - mu * mu;
    const float rstd = rsqrtf(fmaxf(var, 0.f) + 1e-5f);
    float ga[4], gb[4], ba[4], bb[4];
    load4bf(lg + lane * 4, ga);  load4bf(lg + 256 + lane * 4, gb);
    load4bf(lb + lane * 4, ba);  load4bf(lb + 256 + lane * 4, bb);
    ushort_t r0[4], r1[4];
#pragma unroll
    for (int j = 0; j < 4; j++) {
        r0[j] = f2bf((xa[j] - mu) * rstd * ga[j] + ba[j]);
        r1[j] = f2bf((xb[j] - mu) * rstd * gb[j] + bb[j]);
    }
    ushort_t* op = inp + (size_t)row * IN_D;
    uint2 p0, p1;
    p0.x = (unsigned)r0[0] | ((unsigned)r0[1] << 16);
    p0.y = (unsigned)r0[2] | ((unsigned)r0[3] << 16);
    p1.x = (unsigned)r1[0] | ((unsigned)r1[1] << 16);
    p1.y = (unsigned)r1[2] | ((unsigned)r1[3] << 16);
    *(uint2*)(op + lane * 4)       = p0;
    *(uint2*)(op + 256 + lane * 4) = p1;
    op[512 + lane] = gcan[(grow >> 8) * 64 + lane];
}

// ---------- pipelined MFMA GEMM core (templated on M-tiles per wave) ----------
// A[M,*] row-stride lda, Bt[N,K] rm. Block = (MI*16) x 256, 4 waves side-by-side
// in N (wn = wave*64); every wave spans all A rows -> acc[MI][4].
// OPERAND-SWAPPED MFMA: mfma(bg, af) computes C^T in-register, so a thread's
// 4 acc elements are 4 CONSECUTIVE C-COLUMNS at a FIXED row:
//   C row  = m0 + mi*16 + r16
//   C cols = n0 + wn + ni*16 + quad*4 + {0,1,2,3}
// -> epilogue packs uint2/float4 stores (4x fewer store+addr insts).
// Depth-2 prefetch, 3 buffers; counted s_waitcnt vmcnt(LPT) (never 0 in
// steady state); raw s_barrier; inline-asm ds_read_b128 + lgkmcnt(0) +
// sched_barrier(0) (rule 18).
template <int MI>
struct GemmCore {
    floatx4 acc[MI][4];
    int wn, r16, quad;
};

__device__ __forceinline__ void gload16(const ushort_t* g, ushort_t* l) {
    __builtin_amdgcn_global_load_lds(
        (const __attribute__((address_space(1))) unsigned int*)g,
        (__attribute__((address_space(3))) unsigned int*)l, 16, 0, 0);
}
__device__ __forceinline__ unsigned lds_off(const void* p) {
    return (unsigned)(size_t)(const __attribute__((address_space(3))) char*)p;
}

template <int MI>
__device__ __forceinline__ void gemm_core(GemmCore<MI>& g,
        const ushort_t* __restrict__ A, int lda, const ushort_t* __restrict__ Bt,
        int m0, int n0, int K, ushort_t* As, ushort_t* Bs) {
    constexpr int AROWS = MI * 16;          // 128 or 64
    constexpr int A_T   = AROWS * BK;       // elems per A buffer
    constexpr int B_T   = 256 * BK;         // elems per B buffer
    constexpr int ARW   = AROWS / 4;        // A rows staged per wave (32 or 16)
    constexpr int LPT   = AROWS / 64 + 4;   // gload16 per wave per tile (6 or 5)
    const int tid = threadIdx.x;
    const int wave = tid >> 6, lane = tid & 63;
    g.wn = wave * 64; g.r16 = lane & 15; g.quad = lane >> 4;
#pragma unroll
    for (int i = 0; i < MI; i++)
#pragma unroll
        for (int j = 0; j < 4; j++) g.acc[i][j] = (floatx4){0.f, 0.f, 0.f, 0.f};

    const int sr   = lane >> 2;          // 0..15
    const int scol = (lane & 3) * 8;
    const ushort_t* Ag = A  + (size_t)(m0 + wave * ARW + sr) * lda + scol;
    const ushort_t* Bg = Bt + (size_t)(n0 + wave * 64 + sr) * K  + scol;
    ushort_t* Asw = As + wave * ARW * BK;
    ushort_t* Bsw = Bs + wave * 64 * BK;

    const unsigned a_lane = lds_off(As) + (unsigned)((g.r16 * BK + g.quad * 8) * 2);
    const unsigned b_lane = lds_off(Bs) + (unsigned)(((g.wn + g.r16) * BK + g.quad * 8) * 2);

    const int NT = K / BK;
#define STAGE_TILE(T, BUF) do {                                          \
        const size_t kb = (size_t)(T) * BK;                              \
        ushort_t* Ad = Asw + (BUF) * A_T;                                \
        ushort_t* Bd = Bsw + (BUF) * B_T;                                \
        gload16(Ag + kb, Ad);                                            \
        if constexpr (AROWS == 128)                                      \
            gload16(Ag + kb + 16 * (size_t)lda, Ad + 16 * BK);           \
        gload16(Bg + kb,                    Bd);                         \
        gload16(Bg + kb + 16 * (size_t)K,   Bd + 16 * BK);               \
        gload16(Bg + kb + 32 * (size_t)K,   Bd + 32 * BK);               \
        gload16(Bg + kb + 48 * (size_t)K,   Bd + 48 * BK);               \
    } while (0)

    STAGE_TILE(0, 0);
    if (NT > 1) STAGE_TILE(1, 1);

    int bufc = 0;
    for (int t = 0; t < NT; ++t) {
        if (t + 1 < NT) {
            if constexpr (LPT == 6) asm volatile("s_waitcnt vmcnt(6)" ::: "memory");
            else                    asm volatile("s_waitcnt vmcnt(5)" ::: "memory");
        } else {
            asm volatile("s_waitcnt vmcnt(0)" ::: "memory");
        }
        __builtin_amdgcn_s_barrier();
        __builtin_amdgcn_sched_barrier(0);
        if (t + 2 < NT) {                      // prefetch tile t+2 (post-barrier: WAR-safe)
            int bn = bufc + 2; if (bn >= NBUF) bn -= NBUF;
            STAGE_TILE(t + 2, bn);
        }
        const unsigned aaddr = a_lane + (unsigned)(bufc * (A_T * 2));
        const unsigned baddr = b_lane + (unsigned)(bufc * (B_T * 2));
        short8 af[MI], bg[4];
#pragma unroll
        for (int i = 0; i < MI; i++)
            asm volatile("ds_read_b128 %0, %1 offset:%c2"
                         : "=v"(af[i]) : "v"(aaddr), "i"(i * 1024));
#pragma unroll
        for (int i = 0; i < 4; i++)
            asm volatile("ds_read_b128 %0, %1 offset:%c2"
                         : "=v"(bg[i]) : "v"(baddr), "i"(i * 1024));
        asm volatile("s_waitcnt lgkmcnt(0)" ::: "memory");
        __builtin_amdgcn_sched_barrier(0);
#pragma unroll
        for (int mi = 0; mi < MI; mi++)
#pragma unroll
            for (int ni = 0; ni < 4; ni++)
                g.acc[mi][ni] = __builtin_amdgcn_mfma_f32_16x16x32_bf16(
                    bg[ni], af[mi], g.acc[mi][ni], 0, 0, 0);   // SWAPPED -> C^T regs
        bufc = bufc + 1 == NBUF ? 0 : bufc + 1;
    }
#undef STAGE_TILE
}

// out = silu(acc + bias), canonical bf16 out [M,N]; block 128x256
__global__ __launch_bounds__(256, 2)
void gemm_silu(const ushort_t* __restrict__ A, int lda,
               const ushort_t* __restrict__ Bt,
               const ushort_t* __restrict__ bias, ushort_t* __restrict__ out,
               int N, int K) {
    __shared__ __align__(16) ushort_t As[NBUF * 128 * BK];
    __shared__ __align__(16) ushort_t Bs[NBUF * 256 * BK];
    const int m0 = blockIdx.x * 128, n0 = blockIdx.y * 256;
    GemmCore<8> g;
    gemm_core<8>(g, A, lda, Bt, m0, n0, K, As, Bs);
    float bv[4][4];
#pragma unroll
    for (int ni = 0; ni < 4; ni++)
        load4bf(bias + n0 + g.wn + ni * 16 + g.quad * 4, bv[ni]);
#pragma unroll
    for (int mi = 0; mi < 8; mi++) {
        const int row = m0 + mi * 16 + g.r16;
        ushort_t* orow = out + (size_t)row * N + n0 + g.wn + g.quad * 4;
#pragma unroll
        for (int ni = 0; ni < 4; ni++) {
            float v[4];
#pragma unroll
            for (int r = 0; r < 4; r++)
                v[r] = silu_fast(g.acc[mi][ni][r] + bv[ni][r]);
            uint2 p;
            p.x = cvtpk_bf16(v[0], v[1]);
            p.y = cvtpk_bf16(v[2], v[3]);
            *(uint2*)(orow + ni * 16) = p;
        }
    }
}

// out = mask ? acc+bias+resid : resid  (writes d_out in detected dtype)
// block 64x256 (grid CHR/64 -> 2 blocks/CU), full N per block (n0 = 0).
__global__ __launch_bounds__(256, 2)
void gemm_out(const ushort_t* __restrict__ A, int lda,
              const ushort_t* __restrict__ Bt,
              const ushort_t* __restrict__ bias, void* __restrict__ out,
              const void* __restrict__ mask, const void* __restrict__ resid,
              int row0, int K, const int* __restrict__ flags) {
    __shared__ __align__(16) ushort_t As[NBUF * 64 * BK];
    __shared__ __align__(16) ushort_t Bs[NBUF * 256 * BK];
    const int flag = flags[0], flagM = flags[1];
    const int m0 = blockIdx.x * 64;
    GemmCore<4> g;
    gemm_core<4>(g, A, lda, Bt, m0, 0, K, As, Bs);
    float bv[4][4];
#pragma unroll
    for (int ni = 0; ni < 4; ni++)
        load4bf(bias + g.wn + ni * 16 + g.quad * 4, bv[ni]);
#pragma unroll
    for (int mi = 0; mi < 4; mi++) {
        const size_t grow = (size_t)row0 + m0 + mi * 16 + g.r16;
        const bool mk = maskany(mask, grow, flagM);
        const size_t cbase = grow * FEAT_OUT + g.wn + g.quad * 4;
        if (flag) {
            const float* rrow = (const float*)resid + cbase;
            float* orow = (float*)out + cbase;
#pragma unroll
            for (int ni = 0; ni < 4; ni++) {
                float4 nd = *(const float4*)(rrow + ni * 16);
                float4 o;
                o.x = mk ? (g.acc[mi][ni][0] + bv[ni][0] + nd.x) : nd.x;
                o.y = mk ? (g.acc[mi][ni][1] + bv[ni][1] + nd.y) : nd.y;
                o.z = mk ? (g.acc[mi][ni][2] + bv[ni][2] + nd.z) : nd.z;
                o.w = mk ? (g.acc[mi][ni][3] + bv[ni][3] + nd.w) : nd.w;
                *(float4*)(orow + ni * 16) = o;
            }
        } else {
            const ushort_t* rrow = (const ushort_t*)resid + cbase;
            ushort_t* orow = (ushort_t*)out + cbase;
#pragma unroll
            for (int ni = 0; ni < 4; ni++) {
                float nd[4];
                load4bf(rrow + ni * 16, nd);
                float v[4];
#pragma unroll
                for (int r = 0; r < 4; r++)
                    v[r] = mk ? (g.acc[mi][ni][r] + bv[ni][r] + nd[r]) : nd[r];
                uint2 p;
                p.x = cvtpk_bf16(v[0], v[1]);
                p.y = cvtpk_bf16(v[2], v[3]);
                *(uint2*)(orow + ni * 16) = p;
            }
        }
    }
}

// ---------- scores = hcat[.,1024:1280] @ aw2t[4,256]^T + ab2 ----------
__global__ __launch_bounds__(256)
void scores_kernel(const ushort_t* __restrict__ hcat,   // chunk-local [CH,1280]
                   const ushort_t* __restrict__ aw2t,
                   const ushort_t* __restrict__ ab2c,
                   float* __restrict__ scores, int row0) {
    const int row  = blockIdx.x * 4 + (threadIdx.x >> 6);
    const int lane = threadIdx.x & 63;
    float x[4];
    load4bf(hcat + (size_t)row * NCAT + 1024 + lane * 4, x);
    float acc[4];
#pragma unroll
    for (int h = 0; h < 4; h++) {
        float wv[4];
        load4bf(aw2t + h * 256 + lane * 4, wv);
        acc[h] = x[0]*wv[0] + x[1]*wv[1] + x[2]*wv[2] + x[3]*wv[3];
    }
#pragma unroll
    for (int m = 1; m < 64; m <<= 1)
#pragma unroll
        for (int h = 0; h < 4; h++) acc[h] += __shfl_xor(acc[h], m, 64);
    if (lane == 0) {
#pragma unroll
        for (int h = 0; h < 4; h++)
            scores[((size_t)row0 + row) * 4 + h] = acc[h] + bf2f(ab2c[h]);
    }
}

// ---------- masked softmax over the 256 nodes of each graph ----------
__global__ __launch_bounds__(256)
void softmax_kernel(const float* __restrict__ scores, const void* __restrict__ mask,
                    float* __restrict__ w, const int* __restrict__ flags) {
    const int flagM = flags[1];
    const int b = blockIdx.x, n = threadIdx.x;
    const int idx = b * 256 + n;
    float4 s = *(const float4*)(scores + (size_t)idx * 4);
    s.x *= 0.0625f; s.y *= 0.0625f; s.z *= 0.0625f; s.w *= 0.0625f;  // /sqrt(256)
    const bool mk = maskany(mask, idx, flagM);
    __shared__ float4 red[256];
    float4 v;
    v.x = mk ? s.x : -3.0e38f; v.y = mk ? s.y : -3.0e38f;
    v.z = mk ? s.z : -3.0e38f; v.w = mk ? s.w : -3.0e38f;
    red[n] = v; __syncthreads();
    for (int off = 128; off > 0; off >>= 1) {
        if (n < off) {
            float4 o = red[n + off], c = red[n];
            c.x = fmaxf(c.x, o.x); c.y = fmaxf(c.y, o.y);
            c.z = fmaxf(c.z, o.z); c.w = fmaxf(c.w, o.w);
            red[n] = c;
        }
        __syncthreads();
    }
    float4 mx = red[0]; __syncthreads();
    float4 e;
    e.x = mk ? expf(s.x - mx.x) : 0.f; e.y = mk ? expf(s.y - mx.y) : 0.f;
    e.z = mk ? expf(s.z - mx.z) : 0.f; e.w = mk ? expf(s.w - mx.w) : 0.f;
    red[n] = e; __syncthreads();
    for (int off = 128; off > 0; off >>= 1) {
        if (n < off) {
            float4 o = red[n + off], c = red[n];
            c.x += o.x; c.y += o.y; c.z += o.z; c.w += o.w;
            red[n] = c;
        }
        __syncthreads();
    }
    float4 sm = red[0];
    const float ix = (sm.x > 0.f) ? 1.f / sm.x : 0.f;
    const float iy = (sm.y > 0.f) ? 1.f / sm.y : 0.f;
    const float iz = (sm.z > 0.f) ? 1.f / sm.z : 0.f;
    const float iw = (sm.w > 0.f) ? 1.f / sm.w : 0.f;
    float4 r; r.x = e.x * ix; r.y = e.y * iy; r.z = e.z * iz; r.w = e.w * iw;
    *(float4*)(w + (size_t)idx * 4) = r;
}

// ---------- pooled[b][d] = sum_n new_nodes[b,n,d] * w[b,n,d>>6] ----------
__global__ __launch_bounds__(256)
void pooled_kernel(const void* __restrict__ dout, const float* __restrict__ w,
                   const int* __restrict__ flags) {
    const int flag = flags[0];
    const int b = blockIdx.x, t = threadIdx.x;
    __shared__ float wsh[1024];
    const float* wb = w + (size_t)b * 1024;
    for (int i = t; i < 1024; i += 256) wsh[i] = wb[i];
    __syncthreads();
    const int h = t >> 6;
    float acc = 0.f;
    const size_t base = (size_t)b * 65536;
    if (flag) {
        const float* nn = (const float*)dout + base;
#pragma unroll 4
        for (int n = 0; n < 256; n++) acc += nn[(size_t)n * 256 + t] * wsh[n * 4 + h];
        ((float*)dout)[(size_t)ROWS * 256 + (size_t)b * 256 + t] = acc;
    } else {
        const ushort_t* nn = (const ushort_t*)dout + base;
#pragma unroll 4
        for (int n = 0; n < 256; n++) acc += bf2f(nn[(size_t)n * 256 + t]) * wsh[n * 4 + h];
        ((ushort_t*)dout)[(size_t)ROWS * 256 + (size_t)b * 256 + t] = f2bf(acc);
    }
}

extern "C" void kernel_launch(void* const* d_in, const int* in_sizes, int n_in,
                              void* d_out, int out_size, void* d_ws, size_t ws_size,
                              hipStream_t stream) {
    (void)in_sizes; (void)n_in; (void)out_size;
    const void* nodes = d_in[0];
    const void* pe    = d_in[1];
    const void* mask  = d_in[2];
    const void* globs = d_in[3];
    const void* ln_g  = d_in[4];
    const void* ln_b  = d_in[5];
    const void* fw1   = d_in[6];
    const void* fb1   = d_in[7];
    const void* fw2   = d_in[8];
    const void* fb2   = d_in[9];
    const void* aw1   = d_in[10];
    const void* ab1   = d_in[11];
    const void* aw2   = d_in[12];
    const void* ab2   = d_in[13];

    // chunk rows: largest that fits; hcat chunk stays L3-resident.
    int CHR;
    if      (ws_size >= (size_t)140 * 1024 * 1024) CHR = 32768;
    else if (ws_size >= (size_t)80  * 1024 * 1024) CHR = 16384;
    else                                           CHR = 8192;

    char* ws = (char*)d_ws;
    size_t o = 0;
    auto take = [&](size_t bytes) -> char* {
        char* p = ws + o;
        o += (bytes + 255) & ~(size_t)255;
        return p;
    };
    ushort_t* inp  = (ushort_t*)take((size_t)CHR * IN_D * 2);
    ushort_t* hcat = (ushort_t*)take((size_t)CHR * NCAT * 2);
    float*    sc   = (float*)   take((size_t)ROWS * 4 * 4);
    float*    wsm  = (float*)   take((size_t)ROWS * 4 * 4);
    ushort_t* w1cat= (ushort_t*)take((size_t)NCAT * 576 * 2);
    ushort_t* fw2t = (ushort_t*)take(1024 * 256 * 2);
    ushort_t* aw2t = (ushort_t*)take(256 * 4 * 2);
    ushort_t* gcan = (ushort_t*)take(32768 * 2);
    ushort_t* lgc  = (ushort_t*)take(512 * 2);
    ushort_t* lbc  = (ushort_t*)take(512 * 2);
    ushort_t* bcat = (ushort_t*)take((size_t)NCAT * 2);
    ushort_t* fb2c = (ushort_t*)take(256 * 2);
    ushort_t* ab2c = (ushort_t*)take(4 * 2);
    int*      flags= (int*)     take(64);

    detect_kernel<<<1, 256, 0, stream>>>(nodes, mask, flags);
    convert_all<<<139, 256, 0, stream>>>(globs, ln_g, ln_b, fb1, fb2, ab1, ab2,
                                         gcan, lgc, lbc, bcat, fb2c, ab2c, flags);
    transpose_all<<<3908, 256, 0, stream>>>(fw1, fw2, aw1, aw2,
                                            w1cat, fw2t, aw2t, flags);

    const int nchunk = ROWS / CHR;
    for (int c = 0; c < nchunk; c++) {
        const int row0 = c * CHR;
        ln_concat_kernel<<<CHR / 4, 256, 0, stream>>>(nodes, pe, gcan, lgc, lbc,
                                                      inp, row0, flags);
        gemm_silu<<<dim3(CHR / 128, NCAT / 256), 256, 0, stream>>>(
            inp, IN_D, w1cat, bcat, hcat, NCAT, IN_D);
        scores_kernel<<<CHR / 4, 256, 0, stream>>>(hcat, aw2t, ab2c, sc, row0);
        gemm_out<<<dim3(CHR / 64, 1), 256, 0, stream>>>(
            hcat, NCAT, fw2t, fb2c, d_out, mask, nodes, row0, FEAT_HID, flags);
    }

    softmax_kernel<<<B_GRAPH, 256, 0, stream>>>(sc, mask, wsm, flags);
    pooled_kernel<<<B_GRAPH, 256, 0, stream>>>(d_out, wsm, flags);
}